// Round 1
// baseline (1069.433 us; speedup 1.0000x reference)
//
#include <hip/hip_runtime.h>
#include <math.h>

#define L_SEQ 4096
#define D_DIM 768
#define C3    2304
#define TAPS  32

// ---------------- phi: phi[t][f] = sin(10*(pe@W1+b1)), t<32, f<64 ----------------
__global__ __launch_bounds__(256) void phi_kernel(const float* __restrict__ W1,
                                                  const float* __restrict__ b1,
                                                  float* __restrict__ phi) {
  int idx = blockIdx.x * 256 + threadIdx.x;
  if (idx >= TAPS * 64) return;
  int t = idx >> 6, f = idx & 63;
  float tt = (float)t / 4095.0f;
  float s = b1[f];
  #pragma unroll
  for (int e = 0; e < 33; ++e)
    s += sinf(tt * (float)e * 10.0f) * W1[e * 64 + f];
  phi[idx] = sinf(10.0f * s);
}

// ---------------- g[c2][t] = (phi[t]@W2[:,c2] + b2[c2]) * exp(-exp(f_decay[c2])*t*4096/4095) ----------------
__global__ __launch_bounds__(256) void g_kernel(const float* __restrict__ phi,
                                                const float* __restrict__ W2,
                                                const float* __restrict__ b2,
                                                const float* __restrict__ f_decay,
                                                float* __restrict__ g_tab) {
  int idx = blockIdx.x * 256 + threadIdx.x;   // 1536*32
  int c2 = idx >> 5, t = idx & 31;
  float acc = b2[c2];
  #pragma unroll 8
  for (int f = 0; f < 64; ++f)
    acc += phi[t * 64 + f] * W2[f * 1536 + c2];
  float r = expf(f_decay[c2]);
  g_tab[idx] = acc * expf(-r * (float)t * (4096.0f / 4095.0f));
}

// ---------------- GEMM1: projT[b][c][l] = u@W_in + b_in (transposed write) ----------------
#define BM 128
#define BN 128
#define BK 16

__global__ __launch_bounds__(256) void gemm1_kernel(const float* __restrict__ A,     // u (16384 x 768)
                                                    const float* __restrict__ Bm,    // W_in (768 x 2304)
                                                    const float* __restrict__ bias,  // b_in
                                                    float* __restrict__ outT) {      // (4 x 2304 x 4096)
  __shared__ __align__(16) float smem[8192];   // staging: 2x2048 ; epilogue: 64x128 bounce
  float* As = smem;          // [BK][BM]
  float* Bs = smem + 2048;   // [BK][BN]
  const int tid = threadIdx.x;
  const int tx = tid & 15, ty = tid >> 4;
  const int m0 = blockIdx.y * BM;
  const int n0 = blockIdx.x * BN;
  float acc[8][8];
  #pragma unroll
  for (int i = 0; i < 8; ++i)
    #pragma unroll
    for (int j = 0; j < 8; ++j) acc[i][j] = 0.f;

  for (int k0 = 0; k0 < 768; k0 += BK) {
    __syncthreads();
    #pragma unroll
    for (int it = 0; it < 2; ++it) {            // A tile, transpose into As[k][m]
      int idx = tid + it * 256;
      int m_l = idx >> 2, k_l = (idx & 3) * 4;
      const float4 a = *(const float4*)&A[(size_t)(m0 + m_l) * 768 + k0 + k_l];
      As[(k_l + 0) * BM + m_l] = a.x;
      As[(k_l + 1) * BM + m_l] = a.y;
      As[(k_l + 2) * BM + m_l] = a.z;
      As[(k_l + 3) * BM + m_l] = a.w;
    }
    #pragma unroll
    for (int it = 0; it < 2; ++it) {            // B tile direct
      int idx = tid + it * 256;
      int k_l = idx >> 5, n4 = (idx & 31) * 4;
      *(float4*)&Bs[k_l * BN + n4] = *(const float4*)&Bm[(size_t)(k0 + k_l) * 2304 + n0 + n4];
    }
    __syncthreads();
    #pragma unroll
    for (int k = 0; k < BK; ++k) {
      float4 a0 = *(float4*)&As[k * BM + ty * 8];
      float4 a1 = *(float4*)&As[k * BM + ty * 8 + 4];
      float4 b0 = *(float4*)&Bs[k * BN + tx * 8];
      float4 b1 = *(float4*)&Bs[k * BN + tx * 8 + 4];
      float am[8] = {a0.x, a0.y, a0.z, a0.w, a1.x, a1.y, a1.z, a1.w};
      float bn[8] = {b0.x, b0.y, b0.z, b0.w, b1.x, b1.y, b1.z, b1.w};
      #pragma unroll
      for (int i = 0; i < 8; ++i)
        #pragma unroll
        for (int j = 0; j < 8; ++j) acc[i][j] += am[i] * bn[j];
    }
  }
  float bv[8];
  #pragma unroll
  for (int j = 0; j < 8; ++j) bv[j] = bias[n0 + tx * 8 + j];
  const int b  = m0 >> 12;          // m = b*4096 + l, BM divides L
  const int l0 = m0 & 4095;
  #pragma unroll
  for (int half = 0; half < 2; ++half) {
    __syncthreads();
    if ((tx >> 3) == half) {
      int cbase = tx * 8 - half * 64;
      #pragma unroll
      for (int j = 0; j < 8; ++j)
        #pragma unroll
        for (int i = 0; i < 8; ++i)
          smem[(cbase + j) * BM + ty * 8 + i] = acc[i][j] + bv[j];
    }
    __syncthreads();
    #pragma unroll
    for (int it = 0; it < 8; ++it) {
      int idx = tid + it * 256;     // 64 c-rows x 32 float4
      int c_l = idx >> 5, l4 = (idx & 31) * 4;
      int c = n0 + half * 64 + c_l;
      *(float4*)&outT[((size_t)b * C3 + c) * L_SEQ + l0 + l4] = *(float4*)&smem[c_l * BM + l4];
    }
  }
}

// ---------------- row kernel: conv3 + (prefix-sum*f_bias + 32-tap FIR) * gate, both orders ----------------
__device__ __forceinline__ void load_conv(const float* __restrict__ src, float* buf,
                                          float k0, float k1, float k2, float cb, int tid) {
  #pragma unroll
  for (int it = 0; it < 4; ++it) {
    int idx = (tid + it * 256) * 4;
    *(float4*)&buf[32 + idx] = *(const float4*)&src[idx];
  }
  __syncthreads();
  const int base = tid * 16;
  float r[16];
  #pragma unroll
  for (int i = 0; i < 16; ++i)
    r[i] = buf[30 + base + i] * k0 + buf[31 + base + i] * k1 + buf[32 + base + i] * k2 + cb;
  __syncthreads();
  #pragma unroll
  for (int i = 0; i < 16; ++i) buf[32 + base + i] = r[i];
  __syncthreads();
}

__device__ __forceinline__ void order_step(float* bufV, const float* bufX,
                                           const float* sg, float fb, float* scratch, int tid) {
  const int base = tid * 16;
  float w[48];
  #pragma unroll
  for (int j = 0; j < 12; ++j) {
    float4 t4 = *(const float4*)&bufV[base + j * 4];   // v[base-32 .. base+15]
    w[j * 4 + 0] = t4.x; w[j * 4 + 1] = t4.y; w[j * 4 + 2] = t4.z; w[j * 4 + 3] = t4.w;
  }
  float p[16], run = 0.f;
  #pragma unroll
  for (int i = 0; i < 16; ++i) { run += w[32 + i]; p[i] = run; }
  scratch[tid] = run;
  __syncthreads();
  for (int s = 1; s < 256; s <<= 1) {
    float t = (tid >= s) ? scratch[tid - s] : 0.f;
    __syncthreads();
    scratch[tid] += t;
    __syncthreads();
  }
  float off = (tid > 0) ? scratch[tid - 1] : 0.f;
  float y[16];
  #pragma unroll
  for (int i = 0; i < 16; ++i) {
    float a = fb * (off + p[i]);
    #pragma unroll
    for (int t = 0; t < TAPS; ++t) a += sg[t] * w[32 + i - t];
    y[i] = a * bufX[32 + base + i];
  }
  __syncthreads();
  #pragma unroll
  for (int i = 0; i < 16; ++i) bufV[32 + base + i] = y[i];
  __syncthreads();
}

__global__ __launch_bounds__(256) void row_kernel(float* projT,
                                                  const float* __restrict__ conv_k,
                                                  const float* __restrict__ conv_b,
                                                  const float* __restrict__ g_tab,
                                                  const float* __restrict__ f_bias) {
  __shared__ __align__(16) float bufV[32 + L_SEQ];
  __shared__ __align__(16) float bufX[32 + L_SEQ];
  __shared__ float sg[2 * TAPS];
  __shared__ float scratch[256];
  const int tid = threadIdx.x;
  const int b = blockIdx.x / D_DIM, d = blockIdx.x % D_DIM;

  if (tid < 32) { bufV[tid] = 0.f; bufX[tid] = 0.f; }
  if (tid < 64) sg[tid] = g_tab[((size_t)((tid >> 5) * D_DIM + d)) * TAPS + (tid & 31)];
  const float fb0 = f_bias[d];
  const float fb1 = f_bias[D_DIM + d];

  const int cv = 2 * D_DIM + d, cx0 = d, cx1 = D_DIM + d;
  float* rowV        = projT + ((size_t)b * C3 + cv)  * L_SEQ;
  const float* rowX0 = projT + ((size_t)b * C3 + cx0) * L_SEQ;
  const float* rowX1 = projT + ((size_t)b * C3 + cx1) * L_SEQ;

  load_conv(rowV,  bufV, conv_k[cv],  conv_k[C3 + cv],  conv_k[2 * C3 + cv],  conv_b[cv],  tid);
  load_conv(rowX0, bufX, conv_k[cx0], conv_k[C3 + cx0], conv_k[2 * C3 + cx0], conv_b[cx0], tid);
  order_step(bufV, bufX, sg, fb0, scratch, tid);
  load_conv(rowX1, bufX, conv_k[cx1], conv_k[C3 + cx1], conv_k[2 * C3 + cx1], conv_b[cx1], tid);
  order_step(bufV, bufX, sg + TAPS, fb1, scratch, tid);

  #pragma unroll
  for (int it = 0; it < 4; ++it) {
    int idx = (tid + it * 256) * 4;
    *(float4*)&rowV[idx] = *(float4*)&bufV[32 + idx];
  }
}

// ---------------- GEMM2: out[b][l][j] = v2T[b][:,l] . W_out[:,j] + b_out ----------------
__global__ __launch_bounds__(256) void gemm2_kernel(const float* __restrict__ projT,
                                                    const float* __restrict__ Bm,    // W_out 768x768
                                                    const float* __restrict__ bias,  // b_out
                                                    float* __restrict__ out) {
  __shared__ __align__(16) float smem[4096];
  float* As = smem;          // [BK][BM]
  float* Bs = smem + 2048;   // [BK][BN]
  const int tid = threadIdx.x;
  const int tx = tid & 15, ty = tid >> 4;
  const int n0 = blockIdx.x * BN;
  const int l0 = blockIdx.y * BM;
  const int b  = blockIdx.z;
  const float* Abase = projT + ((size_t)b * C3 + 2 * D_DIM) * L_SEQ;  // A[k][m], pitch L
  float acc[8][8];
  #pragma unroll
  for (int i = 0; i < 8; ++i)
    #pragma unroll
    for (int j = 0; j < 8; ++j) acc[i][j] = 0.f;

  for (int k0 = 0; k0 < 768; k0 += BK) {
    __syncthreads();
    #pragma unroll
    for (int it = 0; it < 2; ++it) {            // A tile: already K-major, direct float4
      int idx = tid + it * 256;
      int k_l = idx >> 5, m4 = (idx & 31) * 4;
      *(float4*)&As[k_l * BM + m4] = *(const float4*)&Abase[(size_t)(k0 + k_l) * L_SEQ + l0 + m4];
    }
    #pragma unroll
    for (int it = 0; it < 2; ++it) {
      int idx = tid + it * 256;
      int k_l = idx >> 5, n4 = (idx & 31) * 4;
      *(float4*)&Bs[k_l * BN + n4] = *(const float4*)&Bm[(size_t)(k0 + k_l) * D_DIM + n0 + n4];
    }
    __syncthreads();
    #pragma unroll
    for (int k = 0; k < BK; ++k) {
      float4 a0 = *(float4*)&As[k * BM + ty * 8];
      float4 a1 = *(float4*)&As[k * BM + ty * 8 + 4];
      float4 b0 = *(float4*)&Bs[k * BN + tx * 8];
      float4 b1 = *(float4*)&Bs[k * BN + tx * 8 + 4];
      float am[8] = {a0.x, a0.y, a0.z, a0.w, a1.x, a1.y, a1.z, a1.w};
      float bn[8] = {b0.x, b0.y, b0.z, b0.w, b1.x, b1.y, b1.z, b1.w};
      #pragma unroll
      for (int i = 0; i < 8; ++i)
        #pragma unroll
        for (int j = 0; j < 8; ++j) acc[i][j] += am[i] * bn[j];
    }
  }
  float bv[8];
  #pragma unroll
  for (int j = 0; j < 8; ++j) bv[j] = bias[n0 + tx * 8 + j];
  #pragma unroll
  for (int i = 0; i < 8; ++i) {
    size_t row = ((size_t)b * L_SEQ + l0 + ty * 8 + i) * D_DIM + n0 + tx * 8;
    float4 v0 = {acc[i][0] + bv[0], acc[i][1] + bv[1], acc[i][2] + bv[2], acc[i][3] + bv[3]};
    float4 v1 = {acc[i][4] + bv[4], acc[i][5] + bv[5], acc[i][6] + bv[6], acc[i][7] + bv[7]};
    *(float4*)&out[row]     = v0;
    *(float4*)&out[row + 4] = v1;
  }
}

extern "C" void kernel_launch(void* const* d_in, const int* in_sizes, int n_in,
                              void* d_out, int out_size, void* d_ws, size_t ws_size,
                              hipStream_t stream) {
  (void)in_sizes; (void)n_in; (void)out_size; (void)ws_size;
  const float* u       = (const float*)d_in[0];
  const float* W_in    = (const float*)d_in[1];
  const float* b_in    = (const float*)d_in[2];
  const float* conv_k  = (const float*)d_in[3];
  const float* conv_b  = (const float*)d_in[4];
  const float* W1      = (const float*)d_in[5];
  const float* b1      = (const float*)d_in[6];
  const float* W2      = (const float*)d_in[7];
  const float* b2      = (const float*)d_in[8];
  const float* f_bias  = (const float*)d_in[9];
  const float* f_decay = (const float*)d_in[10];
  const float* W_out   = (const float*)d_in[11];
  const float* b_out   = (const float*)d_in[12];
  float* out = (float*)d_out;

  float* ws     = (float*)d_ws;
  float* projT  = ws;                                   // 4*2304*4096
  float* phi    = ws + (size_t)4 * C3 * L_SEQ;          // 32*64
  float* g_tab  = phi + TAPS * 64;                      // 1536*32

  phi_kernel<<<8, 256, 0, stream>>>(W1, b1, phi);
  g_kernel<<<192, 256, 0, stream>>>(phi, W2, b2, f_decay, g_tab);
  gemm1_kernel<<<dim3(18, 128), 256, 0, stream>>>(u, W_in, b_in, projT);
  row_kernel<<<3072, 256, 0, stream>>>(projT, conv_k, conv_b, g_tab, f_bias);
  gemm2_kernel<<<dim3(6, 32, 4), 256, 0, stream>>>(projT, W_out, b_out, out);
}

// Round 2
// 394.686 us; speedup vs baseline: 2.7096x; 2.7096x over previous
//
#include <hip/hip_runtime.h>
#include <math.h>

#define L_SEQ 4096
#define D_DIM 768
#define C3    2304
#define TAPS  32

typedef __attribute__((ext_vector_type(8))) short bf16x8;
typedef __attribute__((ext_vector_type(4))) float f32x4;

__device__ __forceinline__ unsigned short f2bf(float x) {
  union { float f; unsigned u; } v; v.f = x;
  unsigned r = v.u + 0x7FFF + ((v.u >> 16) & 1);
  return (unsigned short)(r >> 16);
}

__device__ __forceinline__ void gld_lds16(const void* g, void* l) {
  __builtin_amdgcn_global_load_lds((const __attribute__((address_space(1))) void*)g,
                                   (__attribute__((address_space(3))) void*)l, 16, 0, 0);
}

// ---------------- phi: phi[t][f] = sin(10*(pe@W1+b1)), t<32, f<64 ----------------
__global__ __launch_bounds__(256) void phi_kernel(const float* __restrict__ W1,
                                                  const float* __restrict__ b1,
                                                  float* __restrict__ phi) {
  int idx = blockIdx.x * 256 + threadIdx.x;
  if (idx >= TAPS * 64) return;
  int t = idx >> 6, f = idx & 63;
  float tt = (float)t / 4095.0f;
  float s = b1[f];
  #pragma unroll
  for (int e = 0; e < 33; ++e)
    s += sinf(tt * (float)e * 10.0f) * W1[e * 64 + f];
  phi[idx] = sinf(10.0f * s);
}

// ---------------- g[c2][t] = (phi[t]@W2[:,c2] + b2[c2]) * exp(-exp(f_decay[c2])*t*scale) ----------------
__global__ __launch_bounds__(256) void g_kernel(const float* __restrict__ phi,
                                                const float* __restrict__ W2,
                                                const float* __restrict__ b2,
                                                const float* __restrict__ f_decay,
                                                float* __restrict__ g_tab) {
  int idx = blockIdx.x * 256 + threadIdx.x;   // 1536*32
  int c2 = idx >> 5, t = idx & 31;
  float acc = b2[c2];
  #pragma unroll 8
  for (int f = 0; f < 64; ++f)
    acc += phi[t * 64 + f] * W2[f * 1536 + c2];
  float r = expf(f_decay[c2]);
  g_tab[idx] = acc * expf(-r * (float)t * (4096.0f / 4095.0f));
}

// ---------------- cvt u: fp32 -> bf16 ----------------
__global__ __launch_bounds__(256) void cvt_kernel(const float* __restrict__ src,
                                                  unsigned short* __restrict__ dst) {
  int idx = (blockIdx.x * 256 + threadIdx.x) * 4;
  float4 v = *(const float4*)&src[idx];
  ushort4 o;
  o.x = f2bf(v.x); o.y = f2bf(v.y); o.z = f2bf(v.z); o.w = f2bf(v.w);
  *(ushort4*)&dst[idx] = o;
}

// ---------------- transpose+cast: src fp32 [R][C] -> dst bf16 [C][R], batched ----------------
__global__ __launch_bounds__(256) void transpose_cvt(const float* __restrict__ src,
                                                     unsigned short* __restrict__ dst,
                                                     int R, int C, long sbs, long dbs) {
  __shared__ float t[32][33];
  const int c0 = blockIdx.x * 32, r0 = blockIdx.y * 32;
  const long zs = (long)blockIdx.z * sbs, zd = (long)blockIdx.z * dbs;
  const int tx = threadIdx.x & 31, ty = threadIdx.x >> 5;
  #pragma unroll
  for (int rr = 0; rr < 4; ++rr)
    t[ty + rr * 8][tx] = src[zs + (long)(r0 + ty + rr * 8) * C + c0 + tx];
  __syncthreads();
  #pragma unroll
  for (int rr = 0; rr < 4; ++rr)
    dst[zd + (long)(c0 + ty + rr * 8) * R + r0 + tx] = f2bf(t[tx][ty + rr * 8]);
}

// ---------------- GEMM1 (MFMA, Bt layout): projT[b][c][l] = u@W_in + b_in ----------------
// A: bf16 [16384][768], Bt: bf16 [2304][768], out transposed via LDS bounce.
__global__ __launch_bounds__(256) void gemm1_mfma(const unsigned short* __restrict__ A,
                                                  const unsigned short* __restrict__ Bt,
                                                  const float* __restrict__ bias,
                                                  float* __restrict__ outT) {
  __shared__ __align__(16) char smem[17408];
  unsigned short* As = (unsigned short*)smem;     // [128][32]
  unsigned short* Bs = As + 4096;                 // [128][32]
  const int tid = threadIdx.x;
  const int w = tid >> 6, lane = tid & 63;
  const int lr = tid >> 2, lc = tid & 3;          // staging row / 16B-col
  const int m0 = blockIdx.y * 128, n0 = blockIdx.x * 128;
  const int wm = (w & 1) * 64, wn = (w >> 1) * 64;
  const int fm = lane & 15, fk = lane >> 4;
  f32x4 acc[4][4] = {};
  const unsigned short* Ag = A + (size_t)(m0 + lr) * 768 + lc * 8;
  const unsigned short* Bg = Bt + (size_t)(n0 + lr) * 768 + lc * 8;

  for (int k0 = 0; k0 < 768; k0 += 32) {
    __syncthreads();
    gld_lds16(Ag + k0,              (char*)smem + tid * 16);
    gld_lds16(Ag + k0 + 64 * 768,   (char*)smem + 4096 + tid * 16);
    gld_lds16(Bg + k0,              (char*)smem + 8192 + tid * 16);
    gld_lds16(Bg + k0 + 64 * 768,   (char*)smem + 12288 + tid * 16);
    __syncthreads();
    bf16x8 af[4], bfr[4];
    #pragma unroll
    for (int i = 0; i < 4; ++i) af[i]  = *(const bf16x8*)&As[(wm + i * 16 + fm) * 32 + fk * 8];
    #pragma unroll
    for (int j = 0; j < 4; ++j) bfr[j] = *(const bf16x8*)&Bs[(wn + j * 16 + fm) * 32 + fk * 8];
    #pragma unroll
    for (int i = 0; i < 4; ++i)
      #pragma unroll
      for (int j = 0; j < 4; ++j)
        acc[i][j] = __builtin_amdgcn_mfma_f32_16x16x32_bf16(af[i], bfr[j], acc[i][j], 0, 0, 0);
  }

  // epilogue: per-wave 16(n) x 64(m) bounce, pad 68, write [c][l] coalesced
  const int b = m0 >> 12, l0 = m0 & 4095;
  float* fbuf = (float*)smem;                     // 4 waves * 1088 floats
  #pragma unroll
  for (int cg = 0; cg < 4; ++cg) {
    __syncthreads();
    #pragma unroll
    for (int i = 0; i < 4; ++i)
      *(f32x4*)&fbuf[w * 1088 + fm * 68 + i * 16 + fk * 4] = acc[i][cg];
    __syncthreads();
    #pragma unroll
    for (int p = 0; p < 4; ++p) {
      int nl = p * 4 + fk;
      int c = n0 + wn + cg * 16 + nl;
      float4 v = *(float4*)&fbuf[w * 1088 + nl * 68 + fm * 4];
      float bb = bias[c];
      v.x += bb; v.y += bb; v.z += bb; v.w += bb;
      *(float4*)&outT[((size_t)b * C3 + c) * L_SEQ + l0 + wm + fm * 4] = v;
    }
  }
}

// ---------------- GEMM2 (MFMA, Bt layout): out[m][n] = v2F@W_out + b_out ----------------
__global__ __launch_bounds__(256) void gemm2_mfma(const unsigned short* __restrict__ A,
                                                  const unsigned short* __restrict__ Bt,
                                                  const float* __restrict__ bias,
                                                  float* __restrict__ out) {
  __shared__ __align__(16) char smem[16384];
  unsigned short* As = (unsigned short*)smem;
  unsigned short* Bs = As + 4096;
  const int tid = threadIdx.x;
  const int w = tid >> 6, lane = tid & 63;
  const int lr = tid >> 2, lc = tid & 3;
  const int m0 = blockIdx.y * 128, n0 = blockIdx.x * 128;
  const int wm = (w & 1) * 64, wn = (w >> 1) * 64;
  const int fm = lane & 15, fk = lane >> 4;
  f32x4 acc[4][4] = {};
  const unsigned short* Ag = A + (size_t)(m0 + lr) * 768 + lc * 8;
  const unsigned short* Bg = Bt + (size_t)(n0 + lr) * 768 + lc * 8;

  for (int k0 = 0; k0 < 768; k0 += 32) {
    __syncthreads();
    gld_lds16(Ag + k0,              (char*)smem + tid * 16);
    gld_lds16(Ag + k0 + 64 * 768,   (char*)smem + 4096 + tid * 16);
    gld_lds16(Bg + k0,              (char*)smem + 8192 + tid * 16);
    gld_lds16(Bg + k0 + 64 * 768,   (char*)smem + 12288 + tid * 16);
    __syncthreads();
    bf16x8 af[4], bfr[4];
    #pragma unroll
    for (int i = 0; i < 4; ++i) af[i]  = *(const bf16x8*)&As[(wm + i * 16 + fm) * 32 + fk * 8];
    #pragma unroll
    for (int j = 0; j < 4; ++j) bfr[j] = *(const bf16x8*)&Bs[(wn + j * 16 + fm) * 32 + fk * 8];
    #pragma unroll
    for (int i = 0; i < 4; ++i)
      #pragma unroll
      for (int j = 0; j < 4; ++j)
        acc[i][j] = __builtin_amdgcn_mfma_f32_16x16x32_bf16(af[i], bfr[j], acc[i][j], 0, 0, 0);
  }

  #pragma unroll
  for (int j = 0; j < 4; ++j) {
    int n = n0 + wn + j * 16 + fm;
    float bb = bias[n];
    #pragma unroll
    for (int i = 0; i < 4; ++i) {
      int m = m0 + wm + i * 16 + fk * 4;
      #pragma unroll
      for (int r = 0; r < 4; ++r)
        out[(size_t)(m + r) * D_DIM + n] = acc[i][j][r] + bb;
    }
  }
}

// ---------------- row kernel: conv3 + (prefix*f_bias + 32-tap FIR) * gate, both orders ----------------
__device__ __forceinline__ void load_conv(const float* __restrict__ src, float* buf,
                                          float k0, float k1, float k2, float cb, int tid) {
  #pragma unroll
  for (int it = 0; it < 4; ++it) {
    int idx = (tid + it * 256) * 4;
    *(float4*)&buf[32 + idx] = *(const float4*)&src[idx];
  }
  __syncthreads();
  const int base = tid * 16;
  float r[16];
  #pragma unroll
  for (int i = 0; i < 16; ++i)
    r[i] = buf[30 + base + i] * k0 + buf[31 + base + i] * k1 + buf[32 + base + i] * k2 + cb;
  __syncthreads();
  #pragma unroll
  for (int i = 0; i < 16; ++i) buf[32 + base + i] = r[i];
  __syncthreads();
}

__device__ __forceinline__ void order_step(float* bufV, const float* bufX,
                                           const float* sg, float fb, float* scratch, int tid) {
  const int base = tid * 16;
  float w[48];
  #pragma unroll
  for (int j = 0; j < 12; ++j) {
    float4 t4 = *(const float4*)&bufV[base + j * 4];
    w[j * 4 + 0] = t4.x; w[j * 4 + 1] = t4.y; w[j * 4 + 2] = t4.z; w[j * 4 + 3] = t4.w;
  }
  float p[16], run = 0.f;
  #pragma unroll
  for (int i = 0; i < 16; ++i) { run += w[32 + i]; p[i] = run; }
  scratch[tid] = run;
  __syncthreads();
  for (int s = 1; s < 256; s <<= 1) {
    float t = (tid >= s) ? scratch[tid - s] : 0.f;
    __syncthreads();
    scratch[tid] += t;
    __syncthreads();
  }
  float off = (tid > 0) ? scratch[tid - 1] : 0.f;
  float y[16];
  #pragma unroll
  for (int i = 0; i < 16; ++i) {
    float a = fb * (off + p[i]);
    #pragma unroll
    for (int t = 0; t < TAPS; ++t) a += sg[t] * w[32 + i - t];
    y[i] = a * bufX[32 + base + i];
  }
  __syncthreads();
  #pragma unroll
  for (int i = 0; i < 16; ++i) bufV[32 + base + i] = y[i];
  __syncthreads();
}

__global__ __launch_bounds__(256) void row_kernel(float* projT,
                                                  const float* __restrict__ conv_k,
                                                  const float* __restrict__ conv_b,
                                                  const float* __restrict__ g_tab,
                                                  const float* __restrict__ f_bias) {
  __shared__ __align__(16) float bufV[32 + L_SEQ];
  __shared__ __align__(16) float bufX[32 + L_SEQ];
  __shared__ float sg[2 * TAPS];
  __shared__ float scratch[256];
  const int tid = threadIdx.x;
  const int b = blockIdx.x / D_DIM, d = blockIdx.x % D_DIM;

  if (tid < 32) { bufV[tid] = 0.f; bufX[tid] = 0.f; }
  if (tid < 64) sg[tid] = g_tab[((size_t)((tid >> 5) * D_DIM + d)) * TAPS + (tid & 31)];
  const float fb0 = f_bias[d];
  const float fb1 = f_bias[D_DIM + d];

  const int cv = 2 * D_DIM + d, cx0 = d, cx1 = D_DIM + d;
  float* rowV        = projT + ((size_t)b * C3 + cv)  * L_SEQ;
  const float* rowX0 = projT + ((size_t)b * C3 + cx0) * L_SEQ;
  const float* rowX1 = projT + ((size_t)b * C3 + cx1) * L_SEQ;

  load_conv(rowV,  bufV, conv_k[cv],  conv_k[C3 + cv],  conv_k[2 * C3 + cv],  conv_b[cv],  tid);
  load_conv(rowX0, bufX, conv_k[cx0], conv_k[C3 + cx0], conv_k[2 * C3 + cx0], conv_b[cx0], tid);
  order_step(bufV, bufX, sg, fb0, scratch, tid);
  load_conv(rowX1, bufX, conv_k[cx1], conv_k[C3 + cx1], conv_k[2 * C3 + cx1], conv_b[cx1], tid);
  order_step(bufV, bufX, sg + TAPS, fb1, scratch, tid);

  #pragma unroll
  for (int it = 0; it < 4; ++it) {
    int idx = (tid + it * 256) * 4;
    *(float4*)&rowV[idx] = *(float4*)&bufV[32 + idx];
  }
}

extern "C" void kernel_launch(void* const* d_in, const int* in_sizes, int n_in,
                              void* d_out, int out_size, void* d_ws, size_t ws_size,
                              hipStream_t stream) {
  (void)in_sizes; (void)n_in; (void)out_size; (void)ws_size;
  const float* u       = (const float*)d_in[0];
  const float* W_in    = (const float*)d_in[1];
  const float* b_in    = (const float*)d_in[2];
  const float* conv_k  = (const float*)d_in[3];
  const float* conv_b  = (const float*)d_in[4];
  const float* W1      = (const float*)d_in[5];
  const float* b1      = (const float*)d_in[6];
  const float* W2      = (const float*)d_in[7];
  const float* b2      = (const float*)d_in[8];
  const float* f_bias  = (const float*)d_in[9];
  const float* f_decay = (const float*)d_in[10];
  const float* W_out   = (const float*)d_in[11];
  const float* b_out   = (const float*)d_in[12];
  float* out = (float*)d_out;

  float* wsf = (float*)d_ws;
  float* projT          = wsf;                                      // 4*2304*4096 f32
  unsigned short* ubf   = (unsigned short*)(wsf + (size_t)4 * C3 * L_SEQ);  // 16384*768 bf16 (aliased by v2F later)
  unsigned short* v2F   = ubf;
  unsigned short* W_inT = ubf + (size_t)16384 * 768;                // 2304*768 bf16
  unsigned short* W_outT= W_inT + (size_t)C3 * D_DIM;               // 768*768 bf16
  float* phi            = (float*)(W_outT + (size_t)D_DIM * D_DIM);
  float* g_tab          = phi + TAPS * 64;

  phi_kernel<<<8, 256, 0, stream>>>(W1, b1, phi);
  g_kernel<<<192, 256, 0, stream>>>(phi, W2, b2, f_decay, g_tab);
  cvt_kernel<<<12288, 256, 0, stream>>>(u, ubf);                                  // u -> bf16 [m][k]
  transpose_cvt<<<dim3(72, 24, 1), 256, 0, stream>>>(W_in, W_inT, 768, 2304, 0, 0);   // [k][n] -> [n][k]
  transpose_cvt<<<dim3(24, 24, 1), 256, 0, stream>>>(W_out, W_outT, 768, 768, 0, 0);
  gemm1_mfma<<<dim3(18, 128), 256, 0, stream>>>(ubf, W_inT, b_in, projT);
  row_kernel<<<3072, 256, 0, stream>>>(projT, conv_k, conv_b, g_tab, f_bias);
  transpose_cvt<<<dim3(128, 24, 4), 256, 0, stream>>>(projT + (size_t)2 * D_DIM * L_SEQ, v2F,
                                                      768, 4096, (long)C3 * L_SEQ, (long)L_SEQ * D_DIM);
  gemm2_mfma<<<dim3(6, 128), 256, 0, stream>>>(v2F, W_outT, b_out, out);
}

// Round 3
// 377.664 us; speedup vs baseline: 2.8317x; 1.0451x over previous
//
#include <hip/hip_runtime.h>
#include <math.h>

#define L_SEQ 4096
#define D_DIM 768
#define C3    2304
#define TAPS  32

typedef __attribute__((ext_vector_type(8))) short bf16x8;
typedef __attribute__((ext_vector_type(4))) float f32x4;

__device__ __forceinline__ unsigned short f2bf(float x) {
  union { float f; unsigned u; } v; v.f = x;
  unsigned r = v.u + 0x7FFF + ((v.u >> 16) & 1);
  return (unsigned short)(r >> 16);
}
__device__ __forceinline__ float bf2f(unsigned short u) {
  union { unsigned u; float f; } v; v.u = ((unsigned)u) << 16; return v.f;
}
__device__ __forceinline__ void gld_lds16(const void* g, void* l) {
  __builtin_amdgcn_global_load_lds((const __attribute__((address_space(1))) void*)g,
                                   (__attribute__((address_space(3))) void*)l, 16, 0, 0);
}

// ---------------- filter: g_tab[c2][t] for t<32 (decay kills lags >=32) ----------------
__global__ __launch_bounds__(256) void filt_kernel(const float* __restrict__ W1,
                                                   const float* __restrict__ b1,
                                                   const float* __restrict__ W2,
                                                   const float* __restrict__ b2,
                                                   const float* __restrict__ f_decay,
                                                   float* __restrict__ g_tab) {
  __shared__ float phi_s[2048];
  const int tid = threadIdx.x;
  #pragma unroll
  for (int it = 0; it < 8; ++it) {
    int idx = tid + it * 256;
    int t = idx >> 6, f = idx & 63;
    float tt = (float)t / 4095.0f;
    float s = b1[f];
    #pragma unroll
    for (int e = 0; e < 33; ++e)
      s += sinf(tt * (float)e * 10.0f) * W1[e * 64 + f];
    phi_s[idx] = sinf(10.0f * s);
  }
  __syncthreads();
  int idx = blockIdx.x * 256 + tid;        // 1536*32
  int c2 = idx >> 5, t = idx & 31;
  float acc = b2[c2];
  #pragma unroll 8
  for (int f = 0; f < 64; ++f)
    acc += phi_s[t * 64 + f] * W2[f * 1536 + c2];
  float r = expf(f_decay[c2]);
  g_tab[idx] = acc * expf(-r * (float)t * (4096.0f / 4095.0f));
}

// ---------------- cvt u: fp32 -> bf16 ----------------
__global__ __launch_bounds__(256) void cvt_kernel(const float* __restrict__ src,
                                                  unsigned short* __restrict__ dst) {
  int idx = (blockIdx.x * 256 + threadIdx.x) * 4;
  float4 v = *(const float4*)&src[idx];
  ushort4 o;
  o.x = f2bf(v.x); o.y = f2bf(v.y); o.z = f2bf(v.z); o.w = f2bf(v.w);
  *(ushort4*)&dst[idx] = o;
}

// ---------------- weight transposes (both in one launch): fp32 [768][C] -> bf16 [C][768] ----------------
__global__ __launch_bounds__(256) void wtrans_kernel(const float* __restrict__ W_in,
                                                     unsigned short* __restrict__ W_inT,
                                                     const float* __restrict__ W_out,
                                                     unsigned short* __restrict__ W_outT) {
  __shared__ float t[32][33];
  const int z = blockIdx.z;
  const float* src = z ? W_out : W_in;
  unsigned short* dst = z ? W_outT : W_inT;
  const int C = z ? 768 : 2304;
  const int c0 = blockIdx.x * 32, r0 = blockIdx.y * 32;
  if (c0 >= C) return;
  const int tx = threadIdx.x & 31, ty = threadIdx.x >> 5;
  #pragma unroll
  for (int rr = 0; rr < 4; ++rr)
    t[ty + rr * 8][tx] = src[(long)(r0 + ty + rr * 8) * C + c0 + tx];
  __syncthreads();
  #pragma unroll
  for (int rr = 0; rr < 4; ++rr)
    dst[(long)(c0 + ty + rr * 8) * 768 + r0 + tx] = f2bf(t[tx][ty + rr * 8]);
}

// ---------------- GEMM1 (MFMA, dbuf): u@W_in + b_in -> projX (bf16) / projV (f32), transposed ----------------
#define G1_BUF 16384
__global__ __launch_bounds__(256) void gemm1_mfma(const unsigned short* __restrict__ A,
                                                  const unsigned short* __restrict__ Bt,
                                                  const float* __restrict__ bias,
                                                  float* __restrict__ projV,
                                                  unsigned short* __restrict__ projX) {
  __shared__ __align__(16) char smem[32768];
  const int tid = threadIdx.x;
  const int w = tid >> 6, lane = tid & 63;
  const int lr = tid >> 2, lc = tid & 3;
  const int m0 = blockIdx.y * 128, n0 = blockIdx.x * 128;
  const int wm = (w & 1) * 64, wn = (w >> 1) * 64;
  const int fm = lane & 15, fk = lane >> 4;
  f32x4 acc[4][4] = {};
  const unsigned short* Ag = A + (size_t)(m0 + lr) * 768 + lc * 8;
  const unsigned short* Bg = Bt + (size_t)(n0 + lr) * 768 + lc * 8;

  {
    char* dst = smem + tid * 16;
    gld_lds16(Ag,            dst);
    gld_lds16(Ag + 64 * 768, dst + 4096);
    gld_lds16(Bg,            dst + 8192);
    gld_lds16(Bg + 64 * 768, dst + 12288);
  }
  for (int kk = 0; kk < 24; ++kk) {
    const int cur = (kk & 1) * G1_BUF;
    __syncthreads();                      // drains prefetch issued last iter (full iter in flight)
    if (kk < 23) {
      const int k0 = (kk + 1) * 32;
      char* dst = smem + ((kk + 1) & 1) * G1_BUF + tid * 16;
      gld_lds16(Ag + k0,            dst);
      gld_lds16(Ag + k0 + 64 * 768, dst + 4096);
      gld_lds16(Bg + k0,            dst + 8192);
      gld_lds16(Bg + k0 + 64 * 768, dst + 12288);
    }
    const unsigned short* As = (const unsigned short*)(smem + cur);
    const unsigned short* Bs = As + 4096;
    bf16x8 af[4], bfr[4];
    #pragma unroll
    for (int i = 0; i < 4; ++i) af[i]  = *(const bf16x8*)&As[(wm + i * 16 + fm) * 32 + fk * 8];
    #pragma unroll
    for (int j = 0; j < 4; ++j) bfr[j] = *(const bf16x8*)&Bs[(wn + j * 16 + fm) * 32 + fk * 8];
    #pragma unroll
    for (int i = 0; i < 4; ++i)
      #pragma unroll
      for (int j = 0; j < 4; ++j)
        acc[i][j] = __builtin_amdgcn_mfma_f32_16x16x32_bf16(af[i], bfr[j], acc[i][j], 0, 0, 0);
  }

  // epilogue: per-wave 16(n) x 64(m) bounce, pad 68; c<1536 -> bf16 projX, else f32 projV
  const int b = m0 >> 12, l0 = m0 & 4095;
  float* fbuf = (float*)smem;
  const bool isX = (n0 < 1536);
  #pragma unroll
  for (int cg = 0; cg < 4; ++cg) {
    __syncthreads();
    #pragma unroll
    for (int i = 0; i < 4; ++i)
      *(f32x4*)&fbuf[w * 1088 + fm * 68 + i * 16 + fk * 4] = acc[i][cg];
    __syncthreads();
    #pragma unroll
    for (int p = 0; p < 4; ++p) {
      int nl = p * 4 + fk;
      int c = n0 + wn + cg * 16 + nl;
      float4 v = *(float4*)&fbuf[w * 1088 + nl * 68 + fm * 4];
      float bb = bias[c];
      v.x += bb; v.y += bb; v.z += bb; v.w += bb;
      if (isX) {
        ushort4 o;
        o.x = f2bf(v.x); o.y = f2bf(v.y); o.z = f2bf(v.z); o.w = f2bf(v.w);
        *(ushort4*)&projX[((size_t)b * 1536 + c) * L_SEQ + l0 + wm + fm * 4] = o;
      } else {
        *(float4*)&projV[((size_t)b * 768 + (c - 1536)) * L_SEQ + l0 + wm + fm * 4] = v;
      }
    }
  }
}

// ---------------- GEMM2 (MFMA, dbuf): v2F@W_out + b_out -> out, coalesced epilogue ----------------
__global__ __launch_bounds__(256) void gemm2_mfma(const unsigned short* __restrict__ A,
                                                  const unsigned short* __restrict__ Bt,
                                                  const float* __restrict__ bias,
                                                  float* __restrict__ out) {
  __shared__ __align__(16) char smem[32768];
  const int tid = threadIdx.x;
  const int w = tid >> 6, lane = tid & 63;
  const int lr = tid >> 2, lc = tid & 3;
  const int m0 = blockIdx.y * 128, n0 = blockIdx.x * 128;
  const int wm = (w & 1) * 64, wn = (w >> 1) * 64;
  const int fm = lane & 15, fk = lane >> 4;
  f32x4 acc[4][4] = {};
  const unsigned short* Ag = A + (size_t)(m0 + lr) * 768 + lc * 8;
  const unsigned short* Bg = Bt + (size_t)(n0 + lr) * 768 + lc * 8;

  {
    char* dst = smem + tid * 16;
    gld_lds16(Ag,            dst);
    gld_lds16(Ag + 64 * 768, dst + 4096);
    gld_lds16(Bg,            dst + 8192);
    gld_lds16(Bg + 64 * 768, dst + 12288);
  }
  for (int kk = 0; kk < 24; ++kk) {
    const int cur = (kk & 1) * G1_BUF;
    __syncthreads();
    if (kk < 23) {
      const int k0 = (kk + 1) * 32;
      char* dst = smem + ((kk + 1) & 1) * G1_BUF + tid * 16;
      gld_lds16(Ag + k0,            dst);
      gld_lds16(Ag + k0 + 64 * 768, dst + 4096);
      gld_lds16(Bg + k0,            dst + 8192);
      gld_lds16(Bg + k0 + 64 * 768, dst + 12288);
    }
    const unsigned short* As = (const unsigned short*)(smem + cur);
    const unsigned short* Bs = As + 4096;
    bf16x8 af[4], bfr[4];
    #pragma unroll
    for (int i = 0; i < 4; ++i) af[i]  = *(const bf16x8*)&As[(wm + i * 16 + fm) * 32 + fk * 8];
    #pragma unroll
    for (int j = 0; j < 4; ++j) bfr[j] = *(const bf16x8*)&Bs[(wn + j * 16 + fm) * 32 + fk * 8];
    #pragma unroll
    for (int i = 0; i < 4; ++i)
      #pragma unroll
      for (int j = 0; j < 4; ++j)
        acc[i][j] = __builtin_amdgcn_mfma_f32_16x16x32_bf16(af[i], bfr[j], acc[i][j], 0, 0, 0);
  }

  // epilogue: per i, bounce 16(m) x 64(n) per wave, 256B-contiguous stores
  float* fbuf = (float*)smem + w * 1088;    // 16 x 68
  const int nf = lane & 15, mq = lane >> 4;
  float4 bb4 = *(const float4*)&bias[n0 + wn + nf * 4];
  #pragma unroll
  for (int i = 0; i < 4; ++i) {
    __syncthreads();
    #pragma unroll
    for (int cg = 0; cg < 4; ++cg)
      #pragma unroll
      for (int r = 0; r < 4; ++r)
        fbuf[(fk * 4 + r) * 68 + cg * 16 + fm] = acc[i][cg][r];
    __syncthreads();
    #pragma unroll
    for (int pass = 0; pass < 4; ++pass) {
      int m_l = pass * 4 + mq;
      float4 v = *(float4*)&fbuf[m_l * 68 + nf * 4];
      v.x += bb4.x; v.y += bb4.y; v.z += bb4.z; v.w += bb4.w;
      *(float4*)&out[(size_t)(m0 + wm + i * 16 + m_l) * D_DIM + n0 + wn + nf * 4] = v;
    }
  }
}

// ---------------- row kernel ----------------
__device__ __forceinline__ void load_conv(const float* __restrict__ src, float* buf,
                                          float k0, float k1, float k2, float cb, int tid) {
  #pragma unroll
  for (int it = 0; it < 4; ++it) {
    int idx = (tid + it * 256) * 4;
    *(float4*)&buf[32 + idx] = *(const float4*)&src[idx];
  }
  __syncthreads();
  const int base = tid * 16;
  float r[16];
  #pragma unroll
  for (int i = 0; i < 16; ++i)
    r[i] = buf[30 + base + i] * k0 + buf[31 + base + i] * k1 + buf[32 + base + i] * k2 + cb;
  __syncthreads();
  #pragma unroll
  for (int i = 0; i < 16; ++i) buf[32 + base + i] = r[i];
  __syncthreads();
}

__device__ __forceinline__ void load_conv_bf(const unsigned short* __restrict__ src, float* buf,
                                             float k0, float k1, float k2, float cb, int tid) {
  #pragma unroll
  for (int it = 0; it < 2; ++it) {
    int idx = (tid + it * 256) * 8;
    ushort4 a = *(const ushort4*)&src[idx];
    ushort4 c = *(const ushort4*)&src[idx + 4];
    float4 f0; f0.x = bf2f(a.x); f0.y = bf2f(a.y); f0.z = bf2f(a.z); f0.w = bf2f(a.w);
    float4 f1; f1.x = bf2f(c.x); f1.y = bf2f(c.y); f1.z = bf2f(c.z); f1.w = bf2f(c.w);
    *(float4*)&buf[32 + idx] = f0;
    *(float4*)&buf[32 + idx + 4] = f1;
  }
  __syncthreads();
  const int base = tid * 16;
  float r[16];
  #pragma unroll
  for (int i = 0; i < 16; ++i)
    r[i] = buf[30 + base + i] * k0 + buf[31 + base + i] * k1 + buf[32 + base + i] * k2 + cb;
  __syncthreads();
  #pragma unroll
  for (int i = 0; i < 16; ++i) buf[32 + base + i] = r[i];
  __syncthreads();
}

__device__ __forceinline__ void order_step(float* bufV, const float* bufX,
                                           const float* sg, float fb, float* scratch, int tid) {
  const int base = tid * 16;
  float w[48];
  #pragma unroll
  for (int j = 0; j < 12; ++j) {
    float4 t4 = *(const float4*)&bufV[base + j * 4];
    w[j * 4 + 0] = t4.x; w[j * 4 + 1] = t4.y; w[j * 4 + 2] = t4.z; w[j * 4 + 3] = t4.w;
  }
  float p[16], run = 0.f;
  #pragma unroll
  for (int i = 0; i < 16; ++i) { run += w[32 + i]; p[i] = run; }
  scratch[tid] = run;
  __syncthreads();
  for (int s = 1; s < 256; s <<= 1) {
    float t = (tid >= s) ? scratch[tid - s] : 0.f;
    __syncthreads();
    scratch[tid] += t;
    __syncthreads();
  }
  float off = (tid > 0) ? scratch[tid - 1] : 0.f;
  float y[16];
  #pragma unroll
  for (int i = 0; i < 16; ++i) {
    float a = fb * (off + p[i]);
    #pragma unroll
    for (int t = 0; t < TAPS; ++t) a += sg[t] * w[32 + i - t];
    y[i] = a * bufX[32 + base + i];
  }
  __syncthreads();
  #pragma unroll
  for (int i = 0; i < 16; ++i) bufV[32 + base + i] = y[i];
  __syncthreads();
}

__global__ __launch_bounds__(256) void row_kernel(const float* __restrict__ projV,
                                                  const unsigned short* __restrict__ projX,
                                                  unsigned short* __restrict__ v2T,
                                                  const float* __restrict__ conv_k,
                                                  const float* __restrict__ conv_b,
                                                  const float* __restrict__ g_tab,
                                                  const float* __restrict__ f_bias) {
  __shared__ __align__(16) float bufV[32 + L_SEQ];
  __shared__ __align__(16) float bufX[32 + L_SEQ];
  __shared__ float sg[2 * TAPS];
  __shared__ float scratch[256];
  const int tid = threadIdx.x;
  const int b = blockIdx.x / D_DIM, d = blockIdx.x % D_DIM;

  if (tid < 32) { bufV[tid] = 0.f; bufX[tid] = 0.f; }
  if (tid < 64) sg[tid] = g_tab[((size_t)((tid >> 5) * D_DIM + d)) * TAPS + (tid & 31)];
  const float fb0 = f_bias[d];
  const float fb1 = f_bias[D_DIM + d];

  const int cv = 2 * D_DIM + d, cx0 = d, cx1 = D_DIM + d;
  const float* rowV = projV + ((size_t)b * D_DIM + d) * L_SEQ;
  const unsigned short* rowX0 = projX + ((size_t)b * 1536 + d) * L_SEQ;
  const unsigned short* rowX1 = projX + ((size_t)b * 1536 + D_DIM + d) * L_SEQ;

  load_conv(rowV, bufV, conv_k[cv], conv_k[C3 + cv], conv_k[2 * C3 + cv], conv_b[cv], tid);
  load_conv_bf(rowX0, bufX, conv_k[cx0], conv_k[C3 + cx0], conv_k[2 * C3 + cx0], conv_b[cx0], tid);
  order_step(bufV, bufX, sg, fb0, scratch, tid);
  load_conv_bf(rowX1, bufX, conv_k[cx1], conv_k[C3 + cx1], conv_k[2 * C3 + cx1], conv_b[cx1], tid);
  order_step(bufV, bufX, sg + TAPS, fb1, scratch, tid);

  unsigned short* outRow = v2T + ((size_t)b * D_DIM + d) * L_SEQ;
  #pragma unroll
  for (int it = 0; it < 2; ++it) {
    int idx = (tid + it * 256) * 8;
    float4 f0 = *(float4*)&bufV[32 + idx];
    float4 f1 = *(float4*)&bufV[32 + idx + 4];
    ushort4 o0; o0.x = f2bf(f0.x); o0.y = f2bf(f0.y); o0.z = f2bf(f0.z); o0.w = f2bf(f0.w);
    ushort4 o1; o1.x = f2bf(f1.x); o1.y = f2bf(f1.y); o1.z = f2bf(f1.z); o1.w = f2bf(f1.w);
    *(ushort4*)&outRow[idx] = o0;
    *(ushort4*)&outRow[idx + 4] = o1;
  }
}

// ---------------- v2 transpose: bf16 [b][d][l] -> bf16 [b*l][d] ----------------
__global__ __launch_bounds__(256) void transpose_v2(const unsigned short* __restrict__ src,
                                                    unsigned short* __restrict__ dst) {
  __shared__ unsigned short t[64][66];
  const int l0 = blockIdx.x * 64, d0 = blockIdx.y * 64, b = blockIdx.z;
  const int tx = threadIdx.x & 31, ty = threadIdx.x >> 5;
  const unsigned short* s = src + ((size_t)b * D_DIM + d0) * L_SEQ + l0;
  #pragma unroll
  for (int r = 0; r < 8; ++r) {
    int dd = ty + r * 8;
    *(ushort2*)&t[dd][tx * 2] = *(const ushort2*)&s[(size_t)dd * L_SEQ + tx * 2];
  }
  __syncthreads();
  unsigned short* q = dst + ((size_t)b * L_SEQ + l0) * D_DIM + d0;
  #pragma unroll
  for (int r = 0; r < 8; ++r) {
    int ll = ty + r * 8;
    ushort2 v; v.x = t[tx * 2][ll]; v.y = t[tx * 2 + 1][ll];
    *(ushort2*)&q[(size_t)ll * D_DIM + tx * 2] = v;
  }
}

extern "C" void kernel_launch(void* const* d_in, const int* in_sizes, int n_in,
                              void* d_out, int out_size, void* d_ws, size_t ws_size,
                              hipStream_t stream) {
  (void)in_sizes; (void)n_in; (void)out_size; (void)ws_size;
  const float* u       = (const float*)d_in[0];
  const float* W_in    = (const float*)d_in[1];
  const float* b_in    = (const float*)d_in[2];
  const float* conv_k  = (const float*)d_in[3];
  const float* conv_b  = (const float*)d_in[4];
  const float* W1      = (const float*)d_in[5];
  const float* b1      = (const float*)d_in[6];
  const float* W2      = (const float*)d_in[7];
  const float* b2      = (const float*)d_in[8];
  const float* f_bias  = (const float*)d_in[9];
  const float* f_decay = (const float*)d_in[10];
  const float* W_out   = (const float*)d_in[11];
  const float* b_out   = (const float*)d_in[12];
  float* out = (float*)d_out;

  float* projV          = (float*)d_ws;                                  // 4*768*4096 f32
  unsigned short* projX = (unsigned short*)(projV + (size_t)4 * 768 * L_SEQ); // 4*1536*4096 bf16
  unsigned short* v2T   = projX + (size_t)4 * 1536 * L_SEQ;              // 4*768*4096 bf16
  unsigned short* ubf   = v2T + (size_t)4 * 768 * L_SEQ;                 // 16384*768 bf16
  unsigned short* v2F   = ubf;                                           // alias (ubf dead after gemm1)
  unsigned short* W_inT = ubf + (size_t)16384 * 768;                     // 2304*768 bf16
  unsigned short* W_outT= W_inT + (size_t)C3 * D_DIM;                    // 768*768 bf16
  float* g_tab          = (float*)(W_outT + (size_t)D_DIM * D_DIM);      // 1536*32 f32

  filt_kernel<<<192, 256, 0, stream>>>(W1, b1, W2, b2, f_decay, g_tab);
  cvt_kernel<<<12288, 256, 0, stream>>>(u, ubf);
  wtrans_kernel<<<dim3(72, 24, 2), 256, 0, stream>>>(W_in, W_inT, W_out, W_outT);
  gemm1_mfma<<<dim3(18, 128), 256, 0, stream>>>(ubf, W_inT, b_in, projV, projX);
  row_kernel<<<3072, 256, 0, stream>>>(projV, projX, v2T, conv_k, conv_b, g_tab, f_bias);
  transpose_v2<<<dim3(64, 12, 4), 256, 0, stream>>>(v2T, v2F);
  gemm2_mfma<<<dim3(6, 128), 256, 0, stream>>>(v2F, W_outT, b_out, out);
}

// Round 4
// 311.018 us; speedup vs baseline: 3.4385x; 1.2143x over previous
//
#include <hip/hip_runtime.h>
#include <math.h>

#define L_SEQ 4096
#define D_DIM 768
#define C3    2304
#define TAPS  32

typedef __attribute__((ext_vector_type(8))) short bf16x8;
typedef __attribute__((ext_vector_type(4))) float f32x4;

__device__ __forceinline__ unsigned short f2bf(float x) {
  union { float f; unsigned u; } v; v.f = x;
  unsigned r = v.u + 0x7FFF + ((v.u >> 16) & 1);
  return (unsigned short)(r >> 16);
}
__device__ __forceinline__ float bf2f(unsigned short u) {
  union { unsigned u; float f; } v; v.u = ((unsigned)u) << 16; return v.f;
}
__device__ __forceinline__ void gld_lds16(const void* g, void* l) {
  __builtin_amdgcn_global_load_lds((const __attribute__((address_space(1))) void*)g,
                                   (__attribute__((address_space(3))) void*)l, 16, 0, 0);
}

// ---------------- filter: g_tab[c2][t] for t<32 (decay kills lags >=32) ----------------
__global__ __launch_bounds__(256) void filt_kernel(const float* __restrict__ W1,
                                                   const float* __restrict__ b1,
                                                   const float* __restrict__ W2,
                                                   const float* __restrict__ b2,
                                                   const float* __restrict__ f_decay,
                                                   float* __restrict__ g_tab) {
  __shared__ float phi_s[2048];
  const int tid = threadIdx.x;
  #pragma unroll
  for (int it = 0; it < 8; ++it) {
    int idx = tid + it * 256;
    int t = idx >> 6, f = idx & 63;
    float tt = (float)t / 4095.0f;
    float s = b1[f];
    #pragma unroll
    for (int e = 0; e < 33; ++e)
      s += sinf(tt * (float)e * 10.0f) * W1[e * 64 + f];
    phi_s[idx] = sinf(10.0f * s);
  }
  __syncthreads();
  int idx = blockIdx.x * 256 + tid;        // 1536*32
  int c2 = idx >> 5, t = idx & 31;
  float acc = b2[c2];
  #pragma unroll 8
  for (int f = 0; f < 64; ++f)
    acc += phi_s[t * 64 + f] * W2[f * 1536 + c2];
  float r = expf(f_decay[c2]);
  g_tab[idx] = acc * expf(-r * (float)t * (4096.0f / 4095.0f));
}

// ---------------- cvt u: fp32 -> bf16 ----------------
__global__ __launch_bounds__(256) void cvt_kernel(const float* __restrict__ src,
                                                  unsigned short* __restrict__ dst) {
  int idx = (blockIdx.x * 256 + threadIdx.x) * 4;
  float4 v = *(const float4*)&src[idx];
  ushort4 o;
  o.x = f2bf(v.x); o.y = f2bf(v.y); o.z = f2bf(v.z); o.w = f2bf(v.w);
  *(ushort4*)&dst[idx] = o;
}

// ---------------- weight transposes: fp32 [768][C] -> bf16 [C][768] ----------------
__global__ __launch_bounds__(256) void wtrans_kernel(const float* __restrict__ W_in,
                                                     unsigned short* __restrict__ W_inT,
                                                     const float* __restrict__ W_out,
                                                     unsigned short* __restrict__ W_outT) {
  __shared__ float t[32][33];
  const int z = blockIdx.z;
  const float* src = z ? W_out : W_in;
  unsigned short* dst = z ? W_outT : W_inT;
  const int C = z ? 768 : 2304;
  const int c0 = blockIdx.x * 32, r0 = blockIdx.y * 32;
  if (c0 >= C) return;
  const int tx = threadIdx.x & 31, ty = threadIdx.x >> 5;
  #pragma unroll
  for (int rr = 0; rr < 4; ++rr)
    t[ty + rr * 8][tx] = src[(long)(r0 + ty + rr * 8) * C + c0 + tx];
  __syncthreads();
  #pragma unroll
  for (int rr = 0; rr < 4; ++rr)
    dst[(long)(c0 + ty + rr * 8) * 768 + r0 + tx] = f2bf(t[tx][ty + rr * 8]);
}

// ---------------- GEMM1 (MFMA, dbuf): u@W_in + b_in -> projX (bf16) / projV (f32), transposed ----------------
#define G1_BUF 16384
__global__ __launch_bounds__(256) void gemm1_mfma(const unsigned short* __restrict__ A,
                                                  const unsigned short* __restrict__ Bt,
                                                  const float* __restrict__ bias,
                                                  float* __restrict__ projV,
                                                  unsigned short* __restrict__ projX) {
  __shared__ __align__(16) char smem[32768];
  const int tid = threadIdx.x;
  const int w = tid >> 6, lane = tid & 63;
  const int lr = tid >> 2, lc = tid & 3;
  const int m0 = blockIdx.y * 128, n0 = blockIdx.x * 128;
  const int wm = (w & 1) * 64, wn = (w >> 1) * 64;
  const int fm = lane & 15, fk = lane >> 4;
  f32x4 acc[4][4] = {};
  const unsigned short* Ag = A + (size_t)(m0 + lr) * 768 + lc * 8;
  const unsigned short* Bg = Bt + (size_t)(n0 + lr) * 768 + lc * 8;

  {
    char* dst = smem + tid * 16;
    gld_lds16(Ag,            dst);
    gld_lds16(Ag + 64 * 768, dst + 4096);
    gld_lds16(Bg,            dst + 8192);
    gld_lds16(Bg + 64 * 768, dst + 12288);
  }
  for (int kk = 0; kk < 24; ++kk) {
    const int cur = (kk & 1) * G1_BUF;
    __syncthreads();
    if (kk < 23) {
      const int k0 = (kk + 1) * 32;
      char* dst = smem + ((kk + 1) & 1) * G1_BUF + tid * 16;
      gld_lds16(Ag + k0,            dst);
      gld_lds16(Ag + k0 + 64 * 768, dst + 4096);
      gld_lds16(Bg + k0,            dst + 8192);
      gld_lds16(Bg + k0 + 64 * 768, dst + 12288);
    }
    const unsigned short* As = (const unsigned short*)(smem + cur);
    const unsigned short* Bs = As + 4096;
    bf16x8 af[4], bfr[4];
    #pragma unroll
    for (int i = 0; i < 4; ++i) af[i]  = *(const bf16x8*)&As[(wm + i * 16 + fm) * 32 + fk * 8];
    #pragma unroll
    for (int j = 0; j < 4; ++j) bfr[j] = *(const bf16x8*)&Bs[(wn + j * 16 + fm) * 32 + fk * 8];
    #pragma unroll
    for (int i = 0; i < 4; ++i)
      #pragma unroll
      for (int j = 0; j < 4; ++j)
        acc[i][j] = __builtin_amdgcn_mfma_f32_16x16x32_bf16(af[i], bfr[j], acc[i][j], 0, 0, 0);
  }

  const int b = m0 >> 12, l0 = m0 & 4095;
  float* fbuf = (float*)smem;
  const bool isX = (n0 < 1536);
  #pragma unroll
  for (int cg = 0; cg < 4; ++cg) {
    __syncthreads();
    #pragma unroll
    for (int i = 0; i < 4; ++i)
      *(f32x4*)&fbuf[w * 1088 + fm * 68 + i * 16 + fk * 4] = acc[i][cg];
    __syncthreads();
    #pragma unroll
    for (int p = 0; p < 4; ++p) {
      int nl = p * 4 + fk;
      int c = n0 + wn + cg * 16 + nl;
      float4 v = *(float4*)&fbuf[w * 1088 + nl * 68 + fm * 4];
      float bb = bias[c];
      v.x += bb; v.y += bb; v.z += bb; v.w += bb;
      if (isX) {
        ushort4 o;
        o.x = f2bf(v.x); o.y = f2bf(v.y); o.z = f2bf(v.z); o.w = f2bf(v.w);
        *(ushort4*)&projX[((size_t)b * 1536 + c) * L_SEQ + l0 + wm + fm * 4] = o;
      } else {
        *(float4*)&projV[((size_t)b * 768 + (c - 1536)) * L_SEQ + l0 + wm + fm * 4] = v;
      }
    }
  }
}

// ---------------- GEMM2 (MFMA, dbuf): v2F@W_out + b_out -> out ----------------
__global__ __launch_bounds__(256) void gemm2_mfma(const unsigned short* __restrict__ A,
                                                  const unsigned short* __restrict__ Bt,
                                                  const float* __restrict__ bias,
                                                  float* __restrict__ out) {
  __shared__ __align__(16) char smem[32768];
  const int tid = threadIdx.x;
  const int w = tid >> 6, lane = tid & 63;
  const int lr = tid >> 2, lc = tid & 3;
  const int m0 = blockIdx.y * 128, n0 = blockIdx.x * 128;
  const int wm = (w & 1) * 64, wn = (w >> 1) * 64;
  const int fm = lane & 15, fk = lane >> 4;
  f32x4 acc[4][4] = {};
  const unsigned short* Ag = A + (size_t)(m0 + lr) * 768 + lc * 8;
  const unsigned short* Bg = Bt + (size_t)(n0 + lr) * 768 + lc * 8;

  {
    char* dst = smem + tid * 16;
    gld_lds16(Ag,            dst);
    gld_lds16(Ag + 64 * 768, dst + 4096);
    gld_lds16(Bg,            dst + 8192);
    gld_lds16(Bg + 64 * 768, dst + 12288);
  }
  for (int kk = 0; kk < 24; ++kk) {
    const int cur = (kk & 1) * G1_BUF;
    __syncthreads();
    if (kk < 23) {
      const int k0 = (kk + 1) * 32;
      char* dst = smem + ((kk + 1) & 1) * G1_BUF + tid * 16;
      gld_lds16(Ag + k0,            dst);
      gld_lds16(Ag + k0 + 64 * 768, dst + 4096);
      gld_lds16(Bg + k0,            dst + 8192);
      gld_lds16(Bg + k0 + 64 * 768, dst + 12288);
    }
    const unsigned short* As = (const unsigned short*)(smem + cur);
    const unsigned short* Bs = As + 4096;
    bf16x8 af[4], bfr[4];
    #pragma unroll
    for (int i = 0; i < 4; ++i) af[i]  = *(const bf16x8*)&As[(wm + i * 16 + fm) * 32 + fk * 8];
    #pragma unroll
    for (int j = 0; j < 4; ++j) bfr[j] = *(const bf16x8*)&Bs[(wn + j * 16 + fm) * 32 + fk * 8];
    #pragma unroll
    for (int i = 0; i < 4; ++i)
      #pragma unroll
      for (int j = 0; j < 4; ++j)
        acc[i][j] = __builtin_amdgcn_mfma_f32_16x16x32_bf16(af[i], bfr[j], acc[i][j], 0, 0, 0);
  }

  float* fbuf = (float*)smem + w * 1088;
  const int nf = lane & 15, mq = lane >> 4;
  float4 bb4 = *(const float4*)&bias[n0 + wn + nf * 4];
  #pragma unroll
  for (int i = 0; i < 4; ++i) {
    __syncthreads();
    #pragma unroll
    for (int cg = 0; cg < 4; ++cg)
      #pragma unroll
      for (int r = 0; r < 4; ++r)
        fbuf[(fk * 4 + r) * 68 + cg * 16 + fm] = acc[i][cg][r];
    __syncthreads();
    #pragma unroll
    for (int pass = 0; pass < 4; ++pass) {
      int m_l = pass * 4 + mq;
      float4 v = *(float4*)&fbuf[m_l * 68 + nf * 4];
      v.x += bb4.x; v.y += bb4.y; v.z += bb4.z; v.w += bb4.w;
      *(float4*)&out[(size_t)(m0 + wm + i * 16 + m_l) * D_DIM + n0 + wn + nf * 4] = v;
    }
  }
}

// ---------------- row kernel: conflict-free column LDS + shfl scan, 5 barriers ----------------
// Logical conv'd index L (with 32-halo) lives at phys = (L&15)*258 + (L>>4).
// Thread t owns L = 32+16t+i  ->  phys = i*258 + (t+2): bank (2i+t)%32, conflict-free.
__global__ __launch_bounds__(256) void row_kernel(const float* __restrict__ projV,
                                                  const unsigned short* __restrict__ projX,
                                                  unsigned short* __restrict__ v2T,
                                                  const float* __restrict__ conv_k,
                                                  const float* __restrict__ conv_b,
                                                  const float* __restrict__ g_tab,
                                                  const float* __restrict__ f_bias) {
  __shared__ float buf0[4128];
  __shared__ float buf1[4128];
  __shared__ float sgs[2 * TAPS];
  __shared__ float wsum[4];
  __shared__ float bnd[3][4][2];
  const int tid = threadIdx.x;
  const int lane = tid & 63, w = tid >> 6;
  const int b = blockIdx.x / D_DIM, d = blockIdx.x % D_DIM;
  const int g = tid * 16;

  const float* rowV = projV + ((size_t)b * D_DIM + d) * L_SEQ;
  const unsigned short* rowX0 = projX + ((size_t)b * 1536 + d) * L_SEQ;
  const unsigned short* rowX1 = projX + ((size_t)b * 1536 + D_DIM + d) * L_SEQ;

  // ---- global loads into regs (coalesced) ----
  float v[16], x0[16], x1[16];
  #pragma unroll
  for (int k = 0; k < 4; ++k) {
    float4 a = *(const float4*)&rowV[g + k * 4];
    v[k * 4] = a.x; v[k * 4 + 1] = a.y; v[k * 4 + 2] = a.z; v[k * 4 + 3] = a.w;
  }
  #pragma unroll
  for (int k = 0; k < 4; ++k) {
    ushort4 q0 = *(const ushort4*)&rowX0[g + k * 4];
    x0[k * 4] = bf2f(q0.x); x0[k * 4 + 1] = bf2f(q0.y); x0[k * 4 + 2] = bf2f(q0.z); x0[k * 4 + 3] = bf2f(q0.w);
    ushort4 q1 = *(const ushort4*)&rowX1[g + k * 4];
    x1[k * 4] = bf2f(q1.x); x1[k * 4 + 1] = bf2f(q1.y); x1[k * 4 + 2] = bf2f(q1.z); x1[k * 4 + 3] = bf2f(q1.w);
  }

  if (tid < 32) {                    // zero halos (logical L = tid, rows 0..1 of each col)
    int ph = (tid & 15) * 258 + (tid >> 4);
    buf0[ph] = 0.f; buf1[ph] = 0.f;
  }
  if (tid < 64) sgs[tid] = g_tab[((size_t)((tid >> 5) * D_DIM + d)) * TAPS + (tid & 31)];
  if (lane == 63) {
    bnd[0][w][0] = v[14];  bnd[0][w][1] = v[15];
    bnd[1][w][0] = x0[14]; bnd[1][w][1] = x0[15];
    bnd[2][w][0] = x1[14]; bnd[2][w][1] = x1[15];
  }
  const int cv = 2 * D_DIM + d, cx0 = d, cx1 = D_DIM + d;
  const float kv0 = conv_k[cv],  kv1 = conv_k[C3 + cv],  kv2 = conv_k[2 * C3 + cv],  bv = conv_b[cv];
  const float ka0 = conv_k[cx0], ka1 = conv_k[C3 + cx0], ka2 = conv_k[2 * C3 + cx0], ba = conv_b[cx0];
  const float kb0 = conv_k[cx1], kb1 = conv_k[C3 + cx1], kb2 = conv_k[2 * C3 + cx1], bb = conv_b[cx1];
  const float fb0 = f_bias[d], fb1 = f_bias[D_DIM + d];
  __syncthreads();                                         // bar1

  // ---- conv3 in regs (shfl neighbors; wave boundary via bnd) ----
  float vm1 = __shfl_up(v[15], 1),  vm2 = __shfl_up(v[14], 1);
  float am1 = __shfl_up(x0[15], 1), am2 = __shfl_up(x0[14], 1);
  float bm1 = __shfl_up(x1[15], 1), bm2 = __shfl_up(x1[14], 1);
  if (lane == 0) {
    if (w > 0) {
      vm2 = bnd[0][w-1][0]; vm1 = bnd[0][w-1][1];
      am2 = bnd[1][w-1][0]; am1 = bnd[1][w-1][1];
      bm2 = bnd[2][w-1][0]; bm1 = bnd[2][w-1][1];
    } else {
      vm1 = vm2 = am1 = am2 = bm1 = bm2 = 0.f;
    }
  }
  float r[16];
  r[0] = vm2 * kv0 + vm1 * kv1 + v[0] * kv2 + bv;
  r[1] = vm1 * kv0 + v[0] * kv1 + v[1] * kv2 + bv;
  #pragma unroll
  for (int i = 2; i < 16; ++i) r[i] = v[i-2] * kv0 + v[i-1] * kv1 + v[i] * kv2 + bv;
  {
    float t0 = am2 * ka0 + am1 * ka1 + x0[0] * ka2 + ba;
    float t1 = am1 * ka0 + x0[0] * ka1 + x0[1] * ka2 + ba;
    #pragma unroll
    for (int i = 15; i >= 2; --i) x0[i] = x0[i-2] * ka0 + x0[i-1] * ka1 + x0[i] * ka2 + ba;
    x0[0] = t0; x0[1] = t1;
  }
  {
    float t0 = bm2 * kb0 + bm1 * kb1 + x1[0] * kb2 + bb;
    float t1 = bm1 * kb0 + x1[0] * kb1 + x1[1] * kb2 + bb;
    #pragma unroll
    for (int i = 15; i >= 2; --i) x1[i] = x1[i-2] * kb0 + x1[i-1] * kb1 + x1[i] * kb2 + bb;
    x1[0] = t0; x1[1] = t1;
  }
  #pragma unroll
  for (int i = 0; i < 16; ++i) buf0[i * 258 + tid + 2] = r[i];   // conv'd V -> LDS
  __syncthreads();                                         // bar2

  // ---- order 0 ----
  float h[32];
  #pragma unroll
  for (int j = 0; j < 32; ++j) h[j] = buf0[(j & 15) * 258 + tid + (j >> 4)];  // v'[16t-32+j]
  float p[16], run = 0.f;
  #pragma unroll
  for (int i = 0; i < 16; ++i) { run += r[i]; p[i] = run; }
  float s = run;
  #pragma unroll
  for (int off = 1; off < 64; off <<= 1) {
    float o = __shfl_up(s, off);
    if (lane >= off) s += o;
  }
  if (lane == 63) wsum[w] = s;
  __syncthreads();                                         // bar3
  float woff = 0.f;
  #pragma unroll
  for (int k = 0; k < 4; ++k) if (k < w) woff += wsum[k];
  float excl = woff + s - run;
  float y0[16];
  #pragma unroll
  for (int i = 0; i < 16; ++i) {
    float a = fb0 * (excl + p[i]);
    #pragma unroll
    for (int t = 0; t < TAPS; ++t) {
      float vv = (t <= i) ? r[i - t] : h[32 + i - t];
      a += sgs[t] * vv;
    }
    y0[i] = a * x0[i];
  }
  #pragma unroll
  for (int i = 0; i < 16; ++i) buf1[i * 258 + tid + 2] = y0[i];
  __syncthreads();                                         // bar4

  // ---- order 1 ----
  #pragma unroll
  for (int j = 0; j < 32; ++j) h[j] = buf1[(j & 15) * 258 + tid + (j >> 4)];
  run = 0.f;
  #pragma unroll
  for (int i = 0; i < 16; ++i) { run += y0[i]; p[i] = run; }
  s = run;
  #pragma unroll
  for (int off = 1; off < 64; off <<= 1) {
    float o = __shfl_up(s, off);
    if (lane >= off) s += o;
  }
  if (lane == 63) wsum[w] = s;
  __syncthreads();                                         // bar5
  woff = 0.f;
  #pragma unroll
  for (int k = 0; k < 4; ++k) if (k < w) woff += wsum[k];
  excl = woff + s - run;
  unsigned short yout[16];
  #pragma unroll
  for (int i = 0; i < 16; ++i) {
    float a = fb1 * (excl + p[i]);
    #pragma unroll
    for (int t = 0; t < TAPS; ++t) {
      float vv = (t <= i) ? y0[i - t] : h[32 + i - t];
      a += sgs[TAPS + t] * vv;
    }
    yout[i] = f2bf(a * x1[i]);
  }
  unsigned short* outRow = v2T + ((size_t)b * D_DIM + d) * L_SEQ + g;
  *(ushort4*)&outRow[0]  = *(ushort4*)&yout[0];
  *(ushort4*)&outRow[4]  = *(ushort4*)&yout[4];
  *(ushort4*)&outRow[8]  = *(ushort4*)&yout[8];
  *(ushort4*)&outRow[12] = *(ushort4*)&yout[12];
}

// ---------------- v2 transpose: bf16 [b][d][l] -> bf16 [b*l][d] ----------------
__global__ __launch_bounds__(256) void transpose_v2(const unsigned short* __restrict__ src,
                                                    unsigned short* __restrict__ dst) {
  __shared__ unsigned short t[64][66];
  const int l0 = blockIdx.x * 64, d0 = blockIdx.y * 64, b = blockIdx.z;
  const int tx = threadIdx.x & 31, ty = threadIdx.x >> 5;
  const unsigned short* s = src + ((size_t)b * D_DIM + d0) * L_SEQ + l0;
  #pragma unroll
  for (int r = 0; r < 8; ++r) {
    int dd = ty + r * 8;
    *(ushort2*)&t[dd][tx * 2] = *(const ushort2*)&s[(size_t)dd * L_SEQ + tx * 2];
  }
  __syncthreads();
  unsigned short* q = dst + ((size_t)b * L_SEQ + l0) * D_DIM + d0;
  #pragma unroll
  for (int r = 0; r < 8; ++r) {
    int ll = ty + r * 8;
    ushort2 v; v.x = t[tx * 2][ll]; v.y = t[tx * 2 + 1][ll];
    *(ushort2*)&q[(size_t)ll * D_DIM + tx * 2] = v;
  }
}

extern "C" void kernel_launch(void* const* d_in, const int* in_sizes, int n_in,
                              void* d_out, int out_size, void* d_ws, size_t ws_size,
                              hipStream_t stream) {
  (void)in_sizes; (void)n_in; (void)out_size; (void)ws_size;
  const float* u       = (const float*)d_in[0];
  const float* W_in    = (const float*)d_in[1];
  const float* b_in    = (const float*)d_in[2];
  const float* conv_k  = (const float*)d_in[3];
  const float* conv_b  = (const float*)d_in[4];
  const float* W1      = (const float*)d_in[5];
  const float* b1      = (const float*)d_in[6];
  const float* W2      = (const float*)d_in[7];
  const float* b2      = (const float*)d_in[8];
  const float* f_bias  = (const float*)d_in[9];
  const float* f_decay = (const float*)d_in[10];
  const float* W_out   = (const float*)d_in[11];
  const float* b_out   = (const float*)d_in[12];
  float* out = (float*)d_out;

  float* projV          = (float*)d_ws;                                       // 4*768*4096 f32
  unsigned short* projX = (unsigned short*)(projV + (size_t)4 * 768 * L_SEQ); // 4*1536*4096 bf16
  unsigned short* v2T   = projX + (size_t)4 * 1536 * L_SEQ;                   // 4*768*4096 bf16
  unsigned short* ubf   = v2T + (size_t)4 * 768 * L_SEQ;                      // 16384*768 bf16
  unsigned short* v2F   = ubf;                                                // alias (dead after gemm1)
  unsigned short* W_inT = ubf + (size_t)16384 * 768;
  unsigned short* W_outT= W_inT + (size_t)C3 * D_DIM;
  float* g_tab          = (float*)(W_outT + (size_t)D_DIM * D_DIM);

  filt_kernel<<<192, 256, 0, stream>>>(W1, b1, W2, b2, f_decay, g_tab);
  cvt_kernel<<<12288, 256, 0, stream>>>(u, ubf);
  wtrans_kernel<<<dim3(72, 24, 2), 256, 0, stream>>>(W_in, W_inT, W_out, W_outT);
  gemm1_mfma<<<dim3(18, 128), 256, 0, stream>>>(ubf, W_inT, b_in, projV, projX);
  row_kernel<<<3072, 256, 0, stream>>>(projV, projX, v2T, conv_k, conv_b, g_tab, f_bias);
  transpose_v2<<<dim3(64, 12, 4), 256, 0, stream>>>(v2T, v2F);
  gemm2_mfma<<<dim3(6, 128), 256, 0, stream>>>(v2F, W_outT, b_out, out);
}

// Round 6
// 307.495 us; speedup vs baseline: 3.4779x; 1.0115x over previous
//
#include <hip/hip_runtime.h>
#include <math.h>

#define L_SEQ 4096
#define D_DIM 768
#define C3    2304
#define TAPS  32

typedef __attribute__((ext_vector_type(8))) short bf16x8;
typedef __attribute__((ext_vector_type(4))) float f32x4;

__device__ __forceinline__ unsigned short f2bf(float x) {
  union { float f; unsigned u; } v; v.f = x;
  unsigned r = v.u + 0x7FFF + ((v.u >> 16) & 1);
  return (unsigned short)(r >> 16);
}
__device__ __forceinline__ float bf2f(unsigned short u) {
  union { unsigned u; float f; } v; v.u = ((unsigned)u) << 16; return v.f;
}
__device__ __forceinline__ void gld_lds16(const void* g, void* l) {
  __builtin_amdgcn_global_load_lds((const __attribute__((address_space(1))) void*)g,
                                   (__attribute__((address_space(3))) void*)l, 16, 0, 0);
}

// ---------------- filter: g_tab[c2][t] for t<32 (decay kills lags >=32) ----------------
__global__ __launch_bounds__(256) void filt_kernel(const float* __restrict__ W1,
                                                   const float* __restrict__ b1,
                                                   const float* __restrict__ W2,
                                                   const float* __restrict__ b2,
                                                   const float* __restrict__ f_decay,
                                                   float* __restrict__ g_tab) {
  __shared__ float phi_s[2048];
  const int tid = threadIdx.x;
  #pragma unroll
  for (int it = 0; it < 8; ++it) {
    int idx = tid + it * 256;
    int t = idx >> 6, f = idx & 63;
    float tt = (float)t / 4095.0f;
    float s = b1[f];
    #pragma unroll
    for (int e = 0; e < 33; ++e)
      s += sinf(tt * (float)e * 10.0f) * W1[e * 64 + f];
    phi_s[idx] = sinf(10.0f * s);
  }
  __syncthreads();
  int idx = blockIdx.x * 256 + tid;        // 1536*32
  int c2 = idx >> 5, t = idx & 31;
  float acc = b2[c2];
  #pragma unroll 8
  for (int f = 0; f < 64; ++f)
    acc += phi_s[t * 64 + f] * W2[f * 1536 + c2];
  float r = expf(f_decay[c2]);
  g_tab[idx] = acc * expf(-r * (float)t * (4096.0f / 4095.0f));
}

// ---------------- cvt u: fp32 -> bf16 ----------------
__global__ __launch_bounds__(256) void cvt_kernel(const float* __restrict__ src,
                                                  unsigned short* __restrict__ dst) {
  int idx = (blockIdx.x * 256 + threadIdx.x) * 4;
  float4 v = *(const float4*)&src[idx];
  ushort4 o;
  o.x = f2bf(v.x); o.y = f2bf(v.y); o.z = f2bf(v.z); o.w = f2bf(v.w);
  *(ushort4*)&dst[idx] = o;
}

// ---------------- weight transposes: fp32 [768][C] -> bf16 [C][768] ----------------
__global__ __launch_bounds__(256) void wtrans_kernel(const float* __restrict__ W_in,
                                                     unsigned short* __restrict__ W_inT,
                                                     const float* __restrict__ W_out,
                                                     unsigned short* __restrict__ W_outT) {
  __shared__ float t[32][33];
  const int z = blockIdx.z;
  const float* src = z ? W_out : W_in;
  unsigned short* dst = z ? W_outT : W_inT;
  const int C = z ? 768 : 2304;
  const int c0 = blockIdx.x * 32, r0 = blockIdx.y * 32;
  if (c0 >= C) return;
  const int tx = threadIdx.x & 31, ty = threadIdx.x >> 5;
  #pragma unroll
  for (int rr = 0; rr < 4; ++rr)
    t[ty + rr * 8][tx] = src[(long)(r0 + ty + rr * 8) * C + c0 + tx];
  __syncthreads();
  #pragma unroll
  for (int rr = 0; rr < 4; ++rr)
    dst[(long)(c0 + ty + rr * 8) * 768 + r0 + tx] = f2bf(t[tx][ty + rr * 8]);
}

// ---------------- GEMM1 (MFMA, dbuf, XCD swizzle): u@W_in + b_in -> proj bf16 [b][c][l] ----------------
#define G1_BUF 16384
__global__ __launch_bounds__(256) void gemm1_mfma(const unsigned short* __restrict__ A,
                                                  const unsigned short* __restrict__ Bt,
                                                  const float* __restrict__ bias,
                                                  unsigned short* __restrict__ proj) {
  __shared__ __align__(16) char smem[32768];
  const int tid = threadIdx.x;
  const int w = tid >> 6, lane = tid & 63;
  const int lr = tid >> 2, lc = tid & 3;
  // XCD-locality swizzle: XCD x8 owns m-band [x8*16, x8*16+16), sweeps n with A-tiles L2-hot
  const int id = blockIdx.y * 18 + blockIdx.x;
  const int x8 = id & 7, j = id >> 3;           // j in [0,288)
  const int m0 = (x8 * 16 + j / 18) * 128;
  const int n0 = (j % 18) * 128;
  const int wm = (w & 1) * 64, wn = (w >> 1) * 64;
  const int fm = lane & 15, fk = lane >> 4;
  f32x4 acc[4][4] = {};
  const unsigned short* Ag = A + (size_t)(m0 + lr) * 768 + lc * 8;
  const unsigned short* Bg = Bt + (size_t)(n0 + lr) * 768 + lc * 8;

  {
    char* dst = smem + tid * 16;
    gld_lds16(Ag,            dst);
    gld_lds16(Ag + 64 * 768, dst + 4096);
    gld_lds16(Bg,            dst + 8192);
    gld_lds16(Bg + 64 * 768, dst + 12288);
  }
  for (int kk = 0; kk < 24; ++kk) {
    const int cur = (kk & 1) * G1_BUF;
    __syncthreads();
    if (kk < 23) {
      const int k0 = (kk + 1) * 32;
      char* dst = smem + ((kk + 1) & 1) * G1_BUF + tid * 16;
      gld_lds16(Ag + k0,            dst);
      gld_lds16(Ag + k0 + 64 * 768, dst + 4096);
      gld_lds16(Bg + k0,            dst + 8192);
      gld_lds16(Bg + k0 + 64 * 768, dst + 12288);
    }
    const unsigned short* As = (const unsigned short*)(smem + cur);
    const unsigned short* Bs = As + 4096;
    bf16x8 af[4], bfr[4];
    #pragma unroll
    for (int i = 0; i < 4; ++i) af[i]  = *(const bf16x8*)&As[(wm + i * 16 + fm) * 32 + fk * 8];
    #pragma unroll
    for (int j2 = 0; j2 < 4; ++j2) bfr[j2] = *(const bf16x8*)&Bs[(wn + j2 * 16 + fm) * 32 + fk * 8];
    #pragma unroll
    for (int i = 0; i < 4; ++i)
      #pragma unroll
      for (int j2 = 0; j2 < 4; ++j2)
        acc[i][j2] = __builtin_amdgcn_mfma_f32_16x16x32_bf16(af[i], bfr[j2], acc[i][j2], 0, 0, 0);
  }

  const int b = m0 >> 12, l0 = m0 & 4095;
  float* fbuf = (float*)smem;
  #pragma unroll
  for (int cg = 0; cg < 4; ++cg) {
    __syncthreads();
    #pragma unroll
    for (int i = 0; i < 4; ++i)
      *(f32x4*)&fbuf[w * 1088 + fm * 68 + i * 16 + fk * 4] = acc[i][cg];
    __syncthreads();
    #pragma unroll
    for (int p = 0; p < 4; ++p) {
      int nl = p * 4 + fk;
      int c = n0 + wn + cg * 16 + nl;
      float4 v = *(float4*)&fbuf[w * 1088 + nl * 68 + fm * 4];
      float bb = bias[c];
      ushort4 o;
      o.x = f2bf(v.x + bb); o.y = f2bf(v.y + bb); o.z = f2bf(v.z + bb); o.w = f2bf(v.w + bb);
      *(ushort4*)&proj[((size_t)b * C3 + c) * L_SEQ + l0 + wm + fm * 4] = o;
    }
  }
}

// ---------------- GEMM2 (MFMA, dbuf, 64x128 tile): v2F@W_out + b_out -> out ----------------
// Staging: all gld_lds16 dst are base + tid*16 (wave-uniform base + lane*16 — HW requirement).
#define G2_BUF 12288
__global__ __launch_bounds__(256) void gemm2_mfma(const unsigned short* __restrict__ A,
                                                  const unsigned short* __restrict__ Bt,
                                                  const float* __restrict__ bias,
                                                  float* __restrict__ out) {
  __shared__ __align__(16) char smem[24576];
  const int tid = threadIdx.x;
  const int w = tid >> 6, lane = tid & 63;
  const int lr = tid >> 2, lc = tid & 3;
  const int id = blockIdx.y * 6 + blockIdx.x;   // 1536 blocks
  const int x8 = id & 7, j = id >> 3;           // j in [0,192)
  const int m0 = (x8 * 32 + j / 6) * 64;
  const int n0 = (j % 6) * 128;
  const int wm = (w & 1) * 32, wn = (w >> 1) * 64;
  const int fm = lane & 15, fk = lane >> 4;
  f32x4 acc[2][4] = {};
  const unsigned short* Ag = A + (size_t)(m0 + lr) * 768 + lc * 8;   // 64 rows
  const unsigned short* Bg = Bt + (size_t)(n0 + lr) * 768 + lc * 8;  // 128 rows (two 64-row halves)

  {
    char* dst = smem + tid * 16;
    gld_lds16(Ag,            dst);           // A rows 0..63   -> [0,4096)
    gld_lds16(Bg,            dst + 4096);    // B rows 0..63   -> [4096,8192)
    gld_lds16(Bg + 64 * 768, dst + 8192);    // B rows 64..127 -> [8192,12288)
  }
  for (int kk = 0; kk < 24; ++kk) {
    const int cur = (kk & 1) * G2_BUF;
    __syncthreads();
    if (kk < 23) {
      const int k0 = (kk + 1) * 32;
      char* dst = smem + ((kk + 1) & 1) * G2_BUF + tid * 16;
      gld_lds16(Ag + k0,            dst);
      gld_lds16(Bg + k0,            dst + 4096);
      gld_lds16(Bg + k0 + 64 * 768, dst + 8192);
    }
    const unsigned short* As = (const unsigned short*)(smem + cur);
    const unsigned short* Bs = As + 2048;
    bf16x8 af[2], bfr[4];
    #pragma unroll
    for (int i = 0; i < 2; ++i) af[i]  = *(const bf16x8*)&As[(wm + i * 16 + fm) * 32 + fk * 8];
    #pragma unroll
    for (int j2 = 0; j2 < 4; ++j2) bfr[j2] = *(const bf16x8*)&Bs[(wn + j2 * 16 + fm) * 32 + fk * 8];
    #pragma unroll
    for (int i = 0; i < 2; ++i)
      #pragma unroll
      for (int j2 = 0; j2 < 4; ++j2)
        acc[i][j2] = __builtin_amdgcn_mfma_f32_16x16x32_bf16(af[i], bfr[j2], acc[i][j2], 0, 0, 0);
  }

  float* fbuf = (float*)smem + w * 1088;    // 16 x 68 per wave
  const int nf = lane & 15, mq = lane >> 4;
  float4 bb4 = *(const float4*)&bias[n0 + wn + nf * 4];
  #pragma unroll
  for (int i = 0; i < 2; ++i) {
    __syncthreads();
    #pragma unroll
    for (int cg = 0; cg < 4; ++cg)
      #pragma unroll
      for (int r = 0; r < 4; ++r)
        fbuf[(fk * 4 + r) * 68 + cg * 16 + fm] = acc[i][cg][r];
    __syncthreads();
    #pragma unroll
    for (int pass = 0; pass < 4; ++pass) {
      int m_l = pass * 4 + mq;
      float4 v = *(float4*)&fbuf[m_l * 68 + nf * 4];
      v.x += bb4.x; v.y += bb4.y; v.z += bb4.z; v.w += bb4.w;
      *(float4*)&out[(size_t)(m0 + wm + i * 16 + m_l) * D_DIM + n0 + wn + nf * 4] = v;
    }
  }
}

// ---------------- row kernel: conflict-free column LDS + shfl scan ----------------
__global__ __launch_bounds__(256) void row_kernel(const unsigned short* __restrict__ proj,
                                                  unsigned short* __restrict__ v2T,
                                                  const float* __restrict__ conv_k,
                                                  const float* __restrict__ conv_b,
                                                  const float* __restrict__ g_tab,
                                                  const float* __restrict__ f_bias) {
  __shared__ float buf0[4128];
  __shared__ float buf1[4128];
  __shared__ float sgs[2 * TAPS];
  __shared__ float wsum[4];
  __shared__ float bnd[3][4][2];
  const int tid = threadIdx.x;
  const int lane = tid & 63, w = tid >> 6;
  const int b = blockIdx.x / D_DIM, d = blockIdx.x % D_DIM;
  const int g = tid * 16;

  const unsigned short* rowV  = proj + ((size_t)b * C3 + 2 * D_DIM + d) * L_SEQ;
  const unsigned short* rowX0 = proj + ((size_t)b * C3 + d) * L_SEQ;
  const unsigned short* rowX1 = proj + ((size_t)b * C3 + D_DIM + d) * L_SEQ;

  float v[16], x0[16], x1[16];
  #pragma unroll
  for (int k = 0; k < 4; ++k) {
    ushort4 qv = *(const ushort4*)&rowV[g + k * 4];
    v[k * 4] = bf2f(qv.x); v[k * 4 + 1] = bf2f(qv.y); v[k * 4 + 2] = bf2f(qv.z); v[k * 4 + 3] = bf2f(qv.w);
    ushort4 q0 = *(const ushort4*)&rowX0[g + k * 4];
    x0[k * 4] = bf2f(q0.x); x0[k * 4 + 1] = bf2f(q0.y); x0[k * 4 + 2] = bf2f(q0.z); x0[k * 4 + 3] = bf2f(q0.w);
    ushort4 q1 = *(const ushort4*)&rowX1[g + k * 4];
    x1[k * 4] = bf2f(q1.x); x1[k * 4 + 1] = bf2f(q1.y); x1[k * 4 + 2] = bf2f(q1.z); x1[k * 4 + 3] = bf2f(q1.w);
  }

  if (tid < 32) {
    int ph = (tid & 15) * 258 + (tid >> 4);
    buf0[ph] = 0.f; buf1[ph] = 0.f;
  }
  if (tid < 64) sgs[tid] = g_tab[((size_t)((tid >> 5) * D_DIM + d)) * TAPS + (tid & 31)];
  if (lane == 63) {
    bnd[0][w][0] = v[14];  bnd[0][w][1] = v[15];
    bnd[1][w][0] = x0[14]; bnd[1][w][1] = x0[15];
    bnd[2][w][0] = x1[14]; bnd[2][w][1] = x1[15];
  }
  const int cv = 2 * D_DIM + d, cx0 = d, cx1 = D_DIM + d;
  const float kv0 = conv_k[cv],  kv1 = conv_k[C3 + cv],  kv2 = conv_k[2 * C3 + cv],  bv = conv_b[cv];
  const float ka0 = conv_k[cx0], ka1 = conv_k[C3 + cx0], ka2 = conv_k[2 * C3 + cx0], ba = conv_b[cx0];
  const float kb0 = conv_k[cx1], kb1 = conv_k[C3 + cx1], kb2 = conv_k[2 * C3 + cx1], bb = conv_b[cx1];
  const float fb0 = f_bias[d], fb1 = f_bias[D_DIM + d];
  __syncthreads();                                         // bar1

  float vm1 = __shfl_up(v[15], 1),  vm2 = __shfl_up(v[14], 1);
  float am1 = __shfl_up(x0[15], 1), am2 = __shfl_up(x0[14], 1);
  float bm1 = __shfl_up(x1[15], 1), bm2 = __shfl_up(x1[14], 1);
  if (lane == 0) {
    if (w > 0) {
      vm2 = bnd[0][w-1][0]; vm1 = bnd[0][w-1][1];
      am2 = bnd[1][w-1][0]; am1 = bnd[1][w-1][1];
      bm2 = bnd[2][w-1][0]; bm1 = bnd[2][w-1][1];
    } else {
      vm1 = vm2 = am1 = am2 = bm1 = bm2 = 0.f;
    }
  }
  float r[16];
  r[0] = vm2 * kv0 + vm1 * kv1 + v[0] * kv2 + bv;
  r[1] = vm1 * kv0 + v[0] * kv1 + v[1] * kv2 + bv;
  #pragma unroll
  for (int i = 2; i < 16; ++i) r[i] = v[i-2] * kv0 + v[i-1] * kv1 + v[i] * kv2 + bv;
  {
    float t0 = am2 * ka0 + am1 * ka1 + x0[0] * ka2 + ba;
    float t1 = am1 * ka0 + x0[0] * ka1 + x0[1] * ka2 + ba;
    #pragma unroll
    for (int i = 15; i >= 2; --i) x0[i] = x0[i-2] * ka0 + x0[i-1] * ka1 + x0[i] * ka2 + ba;
    x0[0] = t0; x0[1] = t1;
  }
  {
    float t0 = bm2 * kb0 + bm1 * kb1 + x1[0] * kb2 + bb;
    float t1 = bm1 * kb0 + x1[0] * kb1 + x1[1] * kb2 + bb;
    #pragma unroll
    for (int i = 15; i >= 2; --i) x1[i] = x1[i-2] * kb0 + x1[i-1] * kb1 + x1[i] * kb2 + bb;
    x1[0] = t0; x1[1] = t1;
  }
  #pragma unroll
  for (int i = 0; i < 16; ++i) buf0[i * 258 + tid + 2] = r[i];
  __syncthreads();                                         // bar2

  // ---- order 0 ----
  float h[32];
  #pragma unroll
  for (int j = 0; j < 32; ++j) h[j] = buf0[(j & 15) * 258 + tid + (j >> 4)];
  float p[16], run = 0.f;
  #pragma unroll
  for (int i = 0; i < 16; ++i) { run += r[i]; p[i] = run; }
  float s = run;
  #pragma unroll
  for (int off = 1; off < 64; off <<= 1) {
    float o = __shfl_up(s, off);
    if (lane >= off) s += o;
  }
  if (lane == 63) wsum[w] = s;
  __syncthreads();                                         // bar3
  float woff = 0.f;
  #pragma unroll
  for (int k = 0; k < 4; ++k) if (k < w) woff += wsum[k];
  float excl = woff + s - run;
  float y0[16];
  #pragma unroll
  for (int i = 0; i < 16; ++i) {
    float a = fb0 * (excl + p[i]);
    #pragma unroll
    for (int t = 0; t < TAPS; ++t) {
      float vv = (t <= i) ? r[i - t] : h[32 + i - t];
      a += sgs[t] * vv;
    }
    y0[i] = a * x0[i];
  }
  #pragma unroll
  for (int i = 0; i < 16; ++i) buf1[i * 258 + tid + 2] = y0[i];
  __syncthreads();                                         // bar4

  // ---- order 1 ----
  #pragma unroll
  for (int j = 0; j < 32; ++j) h[j] = buf1[(j & 15) * 258 + tid + (j >> 4)];
  run = 0.f;
  #pragma unroll
  for (int i = 0; i < 16; ++i) { run += y0[i]; p[i] = run; }
  s = run;
  #pragma unroll
  for (int off = 1; off < 64; off <<= 1) {
    float o = __shfl_up(s, off);
    if (lane >= off) s += o;
  }
  if (lane == 63) wsum[w] = s;
  __syncthreads();                                         // bar5
  woff = 0.f;
  #pragma unroll
  for (int k = 0; k < 4; ++k) if (k < w) woff += wsum[k];
  excl = woff + s - run;
  unsigned short yout[16];
  #pragma unroll
  for (int i = 0; i < 16; ++i) {
    float a = fb1 * (excl + p[i]);
    #pragma unroll
    for (int t = 0; t < TAPS; ++t) {
      float vv = (t <= i) ? y0[i - t] : h[32 + i - t];
      a += sgs[TAPS + t] * vv;
    }
    yout[i] = f2bf(a * x1[i]);
  }
  unsigned short* outRow = v2T + ((size_t)b * D_DIM + d) * L_SEQ + g;
  *(ushort4*)&outRow[0]  = *(ushort4*)&yout[0];
  *(ushort4*)&outRow[4]  = *(ushort4*)&yout[4];
  *(ushort4*)&outRow[8]  = *(ushort4*)&yout[8];
  *(ushort4*)&outRow[12] = *(ushort4*)&yout[12];
}

// ---------------- v2 transpose: bf16 [b][d][l] -> bf16 [b*l][d] ----------------
__global__ __launch_bounds__(256) void transpose_v2(const unsigned short* __restrict__ src,
                                                    unsigned short* __restrict__ dst) {
  __shared__ unsigned short t[64][66];
  const int l0 = blockIdx.x * 64, d0 = blockIdx.y * 64, b = blockIdx.z;
  const int tx = threadIdx.x & 31, ty = threadIdx.x >> 5;
  const unsigned short* s = src + ((size_t)b * D_DIM + d0) * L_SEQ + l0;
  #pragma unroll
  for (int r = 0; r < 8; ++r) {
    int dd = ty + r * 8;
    *(ushort2*)&t[dd][tx * 2] = *(const ushort2*)&s[(size_t)dd * L_SEQ + tx * 2];
  }
  __syncthreads();
  unsigned short* q = dst + ((size_t)b * L_SEQ + l0) * D_DIM + d0;
  #pragma unroll
  for (int r = 0; r < 8; ++r) {
    int ll = ty + r * 8;
    ushort2 v; v.x = t[tx * 2][ll]; v.y = t[tx * 2 + 1][ll];
    *(ushort2*)&q[(size_t)ll * D_DIM + tx * 2] = v;
  }
}

extern "C" void kernel_launch(void* const* d_in, const int* in_sizes, int n_in,
                              void* d_out, int out_size, void* d_ws, size_t ws_size,
                              hipStream_t stream) {
  (void)in_sizes; (void)n_in; (void)out_size; (void)ws_size;
  const float* u       = (const float*)d_in[0];
  const float* W_in    = (const float*)d_in[1];
  const float* b_in    = (const float*)d_in[2];
  const float* conv_k  = (const float*)d_in[3];
  const float* conv_b  = (const float*)d_in[4];
  const float* W1      = (const float*)d_in[5];
  const float* b1      = (const float*)d_in[6];
  const float* W2      = (const float*)d_in[7];
  const float* b2      = (const float*)d_in[8];
  const float* f_bias  = (const float*)d_in[9];
  const float* f_decay = (const float*)d_in[10];
  const float* W_out   = (const float*)d_in[11];
  const float* b_out   = (const float*)d_in[12];
  float* out = (float*)d_out;

  unsigned short* proj  = (unsigned short*)d_ws;                 // 4*2304*4096 bf16
  unsigned short* v2T   = proj + (size_t)4 * C3 * L_SEQ;         // 4*768*4096 bf16
  unsigned short* ubf   = v2T + (size_t)4 * D_DIM * L_SEQ;       // 16384*768 bf16
  unsigned short* v2F   = ubf;                                   // alias (dead after gemm1)
  unsigned short* W_inT = ubf + (size_t)16384 * 768;
  unsigned short* W_outT= W_inT + (size_t)C3 * D_DIM;
  float* g_tab          = (float*)(W_outT + (size_t)D_DIM * D_DIM);

  filt_kernel<<<192, 256, 0, stream>>>(W1, b1, W2, b2, f_decay, g_tab);
  cvt_kernel<<<12288, 256, 0, stream>>>(u, ubf);
  wtrans_kernel<<<dim3(72, 24, 2), 256, 0, stream>>>(W_in, W_inT, W_out, W_outT);
  gemm1_mfma<<<dim3(18, 128), 256, 0, stream>>>(ubf, W_inT, b_in, proj);
  row_kernel<<<3072, 256, 0, stream>>>(proj, v2T, conv_k, conv_b, g_tab, f_bias);
  transpose_v2<<<dim3(64, 12, 4), 256, 0, stream>>>(v2T, v2F);
  gemm2_mfma<<<dim3(6, 256), 256, 0, stream>>>(v2F, W_outT, b_out, out);
}